// Round 11
// baseline (388.366 us; speedup 1.0000x reference)
//
#include <hip/hip_runtime.h>
#include <hip/hip_bf16.h>

// ---------------------------------------------------------------------------
// BasicCountNet round 11:
//   - mlp rebuilt wave-autonomous (the decomposition that made agg fast):
//     one wave = one 16-row tile, private 8KB LDS slice, NO barriers.
//     stage A (global_load_lds, per-wave vmcnt) -> pass1 (16 col-frags) ->
//     T1 back into same slice (in-wave DS order) -> pass2 -> fp8/pool.
//     launch_bounds(256,4) -> <=128 VGPR -> 16 independent tiles/CU.
//   - pool via LDS block-reduce (mlp2 only, barriers at end).
//   - everything else = R8 (best measured: 236us).
// ---------------------------------------------------------------------------

#define NQ 64
#define EQ 512
#define ND 50000
#define ED 600000
#define FDIM 128
#define HDIM 256

typedef __attribute__((ext_vector_type(8))) short short8;
typedef __attribute__((ext_vector_type(4))) float f32x4;
typedef __attribute__((ext_vector_type(2))) float floatx2;
typedef __attribute__((ext_vector_type(4))) unsigned short us4;
typedef __attribute__((ext_vector_type(2))) unsigned short us2;

__device__ __forceinline__ unsigned short f2bf(float f) {
    union { float f; unsigned u; } v; v.f = f;
    unsigned r = v.u + 0x7FFF + ((v.u >> 16) & 1);   // RNE
    return (unsigned short)(r >> 16);
}
__device__ __forceinline__ float bf2f(unsigned short u) {
    union { unsigned u; float f; } v; v.u = ((unsigned)u) << 16;
    return v.f;
}

// ---------------- weight pack descriptor ----------------
// Wp layout: [ct(16)][kt(KT)][lane(64)][j(8)]; elem = W[kt*32+(l>>4)*8+j][ct*16+(l&15)]

struct PackDesc {
    const float* W[8];
    unsigned short* Wp[8];
    int KT[8];
    int start[9];
};

__device__ __forceinline__ void pack_unit(const PackDesc& pd, int unit, int l) {
    int m = 0;
    while (m < 7 && unit >= pd.start[m + 1]) ++m;
    const int local = unit - pd.start[m];
    const int KT = pd.KT[m];
    const int kt = local % KT;
    const int ct = local / KT;
    const float* W = pd.W[m];
    unsigned short* Wp = pd.Wp[m];
    const int row = kt * 32 + (l >> 4) * 8;
    const int col = ct * 16 + (l & 15);
    short8 v;
#pragma unroll
    for (int j = 0; j < 8; ++j) v[j] = (short)f2bf(W[(size_t)(row + j) * 256 + col]);
    *(short8*)(Wp + (((size_t)(ct * KT + kt)) * 64 + l) * 8) = v;
}

// ---------------- prepass: cvt(x->fp8) + pack weights + count degrees ----------------

__global__ void prepass(const float* __restrict__ xd, const float* __restrict__ xq,
                        unsigned char* __restrict__ x8, long long nd4, long long n4,
                        int cvt_b, PackDesc pd, int pack_units, int pack_b,
                        const int* __restrict__ d_dst, int* __restrict__ d_deg,
                        const int* __restrict__ q_dst, int* __restrict__ q_deg,
                        int d_eb) {
    const int b = blockIdx.x;
    const int tid = threadIdx.x;
    if (b < cvt_b) {
        long long i = (long long)b * 256 + tid;
        if (i >= n4) return;
        const float* src = (i < nd4) ? (xd + i * 4) : (xq + (i - nd4) * 4);
        float4 v = *(const float4*)src;
        int p = __builtin_amdgcn_cvt_pk_fp8_f32(v.x, v.y, 0, false);
        p = __builtin_amdgcn_cvt_pk_fp8_f32(v.z, v.w, p, true);
        *(unsigned*)(x8 + i * 4) = (unsigned)p;
    } else if (b < cvt_b + pack_b) {
        const int unit = (b - cvt_b) * 4 + (tid >> 6);
        if (unit < pack_units) pack_unit(pd, unit, tid & 63);
    } else {
        const int cb = b - cvt_b - pack_b;
        if (cb < d_eb) {
            int e = cb * 256 + tid;
            if (e < ED) atomicAdd(&d_deg[d_dst[e]], 1);
        } else {
            int e = (cb - d_eb) * 256 + tid;
            if (e < EQ) atomicAdd(&q_deg[q_dst[e]], 1);
        }
    }
}

// ---------------- CSR scan/fill (dual) ----------------

__device__ __forceinline__ void scan1_body(const int* deg, int* rowptr, int* bsum,
                                           int n, int blk) {
    __shared__ int sh[256];
    const int t = threadIdx.x;
    const int i = blk * 256 + t;
    const int v = (i < n) ? deg[i] : 0;
    sh[t] = v;
    __syncthreads();
    for (int off = 1; off < 256; off <<= 1) {
        int x = (t >= off) ? sh[t - off] : 0;
        __syncthreads();
        sh[t] += x;
        __syncthreads();
    }
    if (i < n) rowptr[i] = sh[t] - v;
    if (t == 255) bsum[blk] = sh[255];
}

__global__ void scan_phase1_both(const int* __restrict__ d_deg, int* __restrict__ d_rowptr,
                                 int* __restrict__ d_bsum,
                                 const int* __restrict__ q_deg, int* __restrict__ q_rowptr,
                                 int* __restrict__ q_bsum, int dblocks) {
    int b = blockIdx.x;
    if (b < dblocks) scan1_body(d_deg, d_rowptr, d_bsum, ND, b);
    else             scan1_body(q_deg, q_rowptr, q_bsum, NQ, b - dblocks);
}

__device__ __forceinline__ void scan2_body(const int* bsum, int* boff, int* rowptr_n, int nb) {
    __shared__ int sh[256];
    const int t = threadIdx.x;
    const int v = (t < nb) ? bsum[t] : 0;
    sh[t] = v;
    __syncthreads();
    for (int off = 1; off < 256; off <<= 1) {
        int x = (t >= off) ? sh[t - off] : 0;
        __syncthreads();
        sh[t] += x;
        __syncthreads();
    }
    if (t < nb) boff[t] = sh[t] - v;
    if (t == 255) *rowptr_n = sh[255];
}

__global__ void scan_phase2_both(const int* __restrict__ d_bsum, int* __restrict__ d_boff,
                                 int* __restrict__ d_rowptr_n, int d_nb,
                                 const int* __restrict__ q_bsum, int* __restrict__ q_boff,
                                 int* __restrict__ q_rowptr_n, int q_nb) {
    if (blockIdx.x == 0) scan2_body(d_bsum, d_boff, d_rowptr_n, d_nb);
    else                 scan2_body(q_bsum, q_boff, q_rowptr_n, q_nb);
}

__global__ void scan_phase3_both(int* __restrict__ d_rowptr, const int* __restrict__ d_boff,
                                 int* __restrict__ d_cursor,
                                 int* __restrict__ q_rowptr, const int* __restrict__ q_boff,
                                 int* __restrict__ q_cursor, int dblocks) {
    int b = blockIdx.x;
    if (b < dblocks) {
        int i = b * 256 + threadIdx.x;
        if (i < ND) {
            int r = d_rowptr[i] + d_boff[b];
            d_rowptr[i] = r; d_cursor[i] = r;
        }
    } else {
        int i = (b - dblocks) * 256 + threadIdx.x;
        if (i < NQ) {
            int r = q_rowptr[i] + q_boff[b - dblocks];
            q_rowptr[i] = r; q_cursor[i] = r;
        }
    }
}

__global__ void fill_csr_both(const int* __restrict__ d_src, const int* __restrict__ d_dst,
                              int* __restrict__ d_cursor, int* __restrict__ d_csrsrc,
                              const int* __restrict__ q_src, const int* __restrict__ q_dst,
                              int* __restrict__ q_cursor, int* __restrict__ q_csrsrc,
                              int dblocks) {
    int b = blockIdx.x;
    if (b < dblocks) {
        int e = b * 256 + threadIdx.x;
        if (e < ED) {
            int p = atomicAdd(&d_cursor[d_dst[e]], 1);
            d_csrsrc[p] = d_src[e];
        }
    } else {
        int e = (b - dblocks) * 256 + threadIdx.x;
        if (e < EQ) {
            int p = atomicAdd(&q_cursor[q_dst[e]], 1);
            q_csrsrc[p] = q_src[e];
        }
    }
}

// ---------------- agg conv1: fp8 in (128B rows) / bf16 out, 2 nodes per wave ----------------

__global__ void gin_agg_f8_128_dual(const unsigned char* __restrict__ xd,
                                    const int* __restrict__ rpd, const int* __restrict__ csd,
                                    unsigned short* __restrict__ od,
                                    const unsigned char* __restrict__ xq,
                                    const int* __restrict__ rpq, const int* __restrict__ csq,
                                    unsigned short* __restrict__ oq, int ndpair) {
    const unsigned char* x; const int* rowptr; const int* csr; unsigned short* out; int nb;
    if ((int)blockIdx.x < ndpair) { x = xd; rowptr = rpd; csr = csd; out = od; nb = blockIdx.x; }
    else { x = xq; rowptr = rpq; csr = csq; out = oq; nb = blockIdx.x - ndpair; }

    const int t = threadIdx.x;
    const int node = nb * 2 + (t >> 5);
    const int c = t & 31;

    const int beg = rowptr[node];
    const int end = rowptr[node + 1];

    float a0, a1, a2, a3;
    {
        const unsigned w = *(const unsigned*)(x + (size_t)node * 128 + c * 4);
        floatx2 lo = __builtin_amdgcn_cvt_pk_f32_fp8((int)w, false);
        floatx2 hi = __builtin_amdgcn_cvt_pk_f32_fp8((int)w, true);
        a0 = lo[0]; a1 = lo[1]; a2 = hi[0]; a3 = hi[1];
    }
    for (int j = beg; j < end; ++j) {
        const unsigned w = *(const unsigned*)(x + (size_t)csr[j] * 128 + c * 4);
        floatx2 lo = __builtin_amdgcn_cvt_pk_f32_fp8((int)w, false);
        floatx2 hi = __builtin_amdgcn_cvt_pk_f32_fp8((int)w, true);
        a0 += lo[0]; a1 += lo[1]; a2 += hi[0]; a3 += hi[1];
    }
    us4 r;
    r[0] = f2bf(a0); r[1] = f2bf(a1); r[2] = f2bf(a2); r[3] = f2bf(a3);
    *(us4*)(out + (size_t)node * 128 + c * 4) = r;
}

// ---------------- agg conv2: fp8 in (256B rows) / bf16 out, 1 node per wave ----------------

__global__ void gin_agg_f8_256_dual(const unsigned char* __restrict__ xd,
                                    const int* __restrict__ rpd, const int* __restrict__ csd,
                                    unsigned short* __restrict__ od,
                                    const unsigned char* __restrict__ xq,
                                    const int* __restrict__ rpq, const int* __restrict__ csq,
                                    unsigned short* __restrict__ oq) {
    const unsigned char* x; const int* rowptr; const int* csr; unsigned short* out; int node;
    if ((int)blockIdx.x < ND) { x = xd; rowptr = rpd; csr = csd; out = od; node = blockIdx.x; }
    else { x = xq; rowptr = rpq; csr = csq; out = oq; node = blockIdx.x - ND; }

    const int t = threadIdx.x;
    const int beg = rowptr[node];
    const int end = rowptr[node + 1];

    float a0, a1, a2, a3;
    {
        const unsigned w = *(const unsigned*)(x + (size_t)node * 256 + t * 4);
        floatx2 lo = __builtin_amdgcn_cvt_pk_f32_fp8((int)w, false);
        floatx2 hi = __builtin_amdgcn_cvt_pk_f32_fp8((int)w, true);
        a0 = lo[0]; a1 = lo[1]; a2 = hi[0]; a3 = hi[1];
    }
    int j = beg;
    for (; j + 1 < end; j += 2) {
        const unsigned w0 = *(const unsigned*)(x + (size_t)csr[j] * 256 + t * 4);
        const unsigned w1 = *(const unsigned*)(x + (size_t)csr[j + 1] * 256 + t * 4);
        floatx2 l0 = __builtin_amdgcn_cvt_pk_f32_fp8((int)w0, false);
        floatx2 h0 = __builtin_amdgcn_cvt_pk_f32_fp8((int)w0, true);
        floatx2 l1 = __builtin_amdgcn_cvt_pk_f32_fp8((int)w1, false);
        floatx2 h1 = __builtin_amdgcn_cvt_pk_f32_fp8((int)w1, true);
        a0 += l0[0] + l1[0]; a1 += l0[1] + l1[1];
        a2 += h0[0] + h1[0]; a3 += h0[1] + h1[1];
    }
    if (j < end) {
        const unsigned w0 = *(const unsigned*)(x + (size_t)csr[j] * 256 + t * 4);
        floatx2 l0 = __builtin_amdgcn_cvt_pk_f32_fp8((int)w0, false);
        floatx2 h0 = __builtin_amdgcn_cvt_pk_f32_fp8((int)w0, true);
        a0 += l0[0]; a1 += l0[1]; a2 += h0[0]; a3 += h0[1];
    }
    us4 r;
    r[0] = f2bf(a0); r[1] = f2bf(a1); r[2] = f2bf(a2); r[3] = f2bf(a3);
    *(us4*)(out + (size_t)node * 256 + t * 4) = r;
}

// ---------------- fused MLP: wave-autonomous 16-row tiles, no barriers ----------------
// wave g = blockIdx*4+wv owns rows [g*16, g*16+16) of its graph.
// stage A -> slice; pass1 (16 col-frags x KT1); T1 back to slice; pass2; fp8/pool.

template <int KIN>
__global__ __launch_bounds__(256, 4) void mlp_dual(
    const unsigned short* __restrict__ Ad,
    const unsigned short* __restrict__ W1pd, const float* __restrict__ b1d,
    const unsigned short* __restrict__ W2pd, const float* __restrict__ b2d,
    unsigned char* __restrict__ C8d, float* __restrict__ poold, int ndt,
    const unsigned short* __restrict__ Aq,
    const unsigned short* __restrict__ W1pq, const float* __restrict__ b1q,
    const unsigned short* __restrict__ W2pq, const float* __restrict__ b2q,
    unsigned char* __restrict__ C8q, float* __restrict__ poolq,
    int relu_out, int total_tiles) {
    constexpr int KT1 = KIN / 32;
    constexpr int ISSUES = KIN / 32;        // 1KB global_load_lds chunks per 16xKIN tile
    constexpr int LPR = KIN / 8;            // 16B units per row
    constexpr int RPC = 1024 / (2 * KIN);   // rows per 1KB chunk
    __shared__ __align__(16) unsigned short lds[4][16 * 256];  // 8KB private slice per wave
    __shared__ float poolsh[2][256];

    const int tid = threadIdx.x;
    const int lane = tid & 63;
    const int wv = tid >> 6;
    const int lrow = lane & 15;
    const int lk2 = (lane >> 4) * 8;

    const bool do_pool = (poold != nullptr) || (poolq != nullptr);
    if (do_pool) {
        ((float*)poolsh)[tid] = 0.f;
        ((float*)poolsh)[tid + 256] = 0.f;
        __syncthreads();
    }

    const int g = (int)blockIdx.x * 4 + wv;
    if (g < total_tiles) {
        const unsigned short *A, *W1p, *W2p; const float *b1, *b2;
        unsigned char* C8; int row0, graph;
        if (g < ndt) {
            A = Ad; W1p = W1pd; b1 = b1d; W2p = W2pd; b2 = b2d; C8 = C8d;
            graph = 0; row0 = g * 16;
        } else {
            A = Aq; W1p = W1pq; b1 = b1q; W2p = W2pq; b2 = b2q; C8 = C8q;
            graph = 1; row0 = (g - ndt) * 16;
        }
        unsigned short* slice = &lds[wv][0];

        // ---- stage: 16 x KIN bf16, linear LDS dest, inverse-swizzled global src ----
        {
            const char* Abase = (const char*)A + (size_t)row0 * KIN * 2;
            const int rl = lane / LPR;       // row within chunk
            const int cc = lane % LPR;       // 16B unit within row
#pragma unroll
            for (int i = 0; i < ISSUES; ++i) {
                const int r = i * RPC + rl;
                const char* src = Abase + (size_t)r * (2 * KIN) + ((size_t)(cc ^ (r & 7)) << 4);
                __builtin_amdgcn_global_load_lds(src, (char*)slice + i * 1024, 16, 0, 0);
            }
        }
        asm volatile("s_waitcnt vmcnt(0)" ::: "memory");

        // ---- pass 1: acc1[fn] over 16 col-frags, A-frag shared across fn ----
        f32x4 acc1[16];
#pragma unroll
        for (int fn = 0; fn < 16; ++fn) acc1[fn] = (f32x4)(0.f);

        for (int kt = 0; kt < KT1; ++kt) {
            const unsigned byte =
                (unsigned)((lrow * KIN + kt * 32 + lk2) * 2) ^ (unsigned)((lrow & 7) << 4);
            const short8 a = *(const short8*)((const char*)slice + byte);
#pragma unroll
            for (int fn = 0; fn < 16; ++fn) {
                const short8 bf = *(const short8*)(W1p + (((size_t)(fn * KT1 + kt)) * 64 + lane) * 8);
                acc1[fn] = __builtin_amdgcn_mfma_f32_16x16x32_bf16(a, bf, acc1[fn], 0, 0, 0);
            }
        }

        // ---- T1 (bias+relu, bf16) into slice [16][256], same swizzle (in-wave order) ----
#pragma unroll
        for (int fn = 0; fn < 16; ++fn) {
            const int col = fn * 16 + lrow;
            const float bv = b1[col];
#pragma unroll
            for (int r = 0; r < 4; ++r) {
                const int row = (lane >> 4) * 4 + r;
                const float v = fmaxf(acc1[fn][r] + bv, 0.f);
                const unsigned byte =
                    (unsigned)((row * 256 + col) * 2) ^ (unsigned)((row & 7) << 4);
                *(unsigned short*)((char*)slice + byte) = f2bf(v);
            }
        }

        // ---- pass 2 ----
        f32x4 acc2[16];
#pragma unroll
        for (int fn = 0; fn < 16; ++fn) acc2[fn] = (f32x4)(0.f);

        for (int kt = 0; kt < 8; ++kt) {
            const unsigned byte =
                (unsigned)((lrow * 256 + kt * 32 + lk2) * 2) ^ (unsigned)((lrow & 7) << 4);
            const short8 a = *(const short8*)((const char*)slice + byte);
#pragma unroll
            for (int fn = 0; fn < 16; ++fn) {
                const short8 bf = *(const short8*)(W2p + (((size_t)(fn * 8 + kt)) * 64 + lane) * 8);
                acc2[fn] = __builtin_amdgcn_mfma_f32_16x16x32_bf16(a, bf, acc2[fn], 0, 0, 0);
            }
        }

        // ---- epilogue: bias2 (+relu_out), fp8 store / LDS pool ----
#pragma unroll
        for (int fn = 0; fn < 16; ++fn) {
            const int col = fn * 16 + lrow;
            const float bv = b2[col];
            float ps = 0.f;
#pragma unroll
            for (int r = 0; r < 4; ++r) {
                const int row = (lane >> 4) * 4 + r;
                float v = acc2[fn][r] + bv;
                if (relu_out) v = fmaxf(v, 0.f);
                if (C8) {
                    unsigned p = (unsigned)__builtin_amdgcn_cvt_pk_fp8_f32(v, v, 0, false);
                    C8[(size_t)(row0 + row) * 256 + col] = (unsigned char)(p & 0xff);
                }
                ps += v;
            }
            if (do_pool) {
                ps += __shfl_xor(ps, 16);
                ps += __shfl_xor(ps, 32);
                if ((lane >> 4) == 0) atomicAdd(&poolsh[graph][col], ps);
            }
        }
    }

    if (do_pool) {
        __syncthreads();
        const float vd = poolsh[0][tid & 255];
        const float vq = poolsh[1][tid & 255];
        if (tid < 256) {
            if (poold && vd != 0.f) atomicAdd(&poold[tid], vd);
            if (poolq && vq != 0.f) atomicAdd(&poolq[tid], vq);
        }
    }
}

// ---------------- head ----------------

__global__ void mlp_head(const float* __restrict__ pooled,
                         const float* __restrict__ lW1, const float* __restrict__ lb1,
                         const float* __restrict__ lW2, const float* __restrict__ lb2,
                         const float* __restrict__ lW3, const float* __restrict__ lb3,
                         float* __restrict__ out) {
    __shared__ float h0[512];
    __shared__ float h1[256];
    __shared__ float h2[128];
    const int t = threadIdx.x;  // 256 threads
    h0[t] = pooled[t];
    h0[t + 256] = pooled[t + 256];
    __syncthreads();

    float acc = lb1[t];
    for (int k = 0; k < 512; ++k) acc += h0[k] * lW1[k * 256 + t];
    h1[t] = fmaxf(acc, 0.f);
    __syncthreads();

    if (t < 128) {
        float a = lb2[t];
        for (int k = 0; k < 256; ++k) a += h1[k] * lW2[k * 128 + t];
        h2[t] = fmaxf(a, 0.f);
    }
    __syncthreads();

    if (t < 8) {
        float a = lb3[t];
        for (int k = 0; k < 128; ++k) a += h2[k] * lW3[k * 8 + t];
        out[t] = fmaxf(a, 0.f);
    }
}

// ---------------------------------------------------------------------------

extern "C" void kernel_launch(void* const* d_in, const int* in_sizes, int n_in,
                              void* d_out, int out_size, void* d_ws, size_t ws_size,
                              hipStream_t stream) {
    const float* q_x  = (const float*)d_in[0];
    const float* d_x  = (const float*)d_in[1];
    const int*   q_el = (const int*)d_in[2];
    const int*   d_el = (const int*)d_in[3];
    const float* qW1 = (const float*)d_in[4];  const float* qb1 = (const float*)d_in[5];
    const float* qW2 = (const float*)d_in[6];  const float* qb2 = (const float*)d_in[7];
    const float* qW3 = (const float*)d_in[8];  const float* qb3 = (const float*)d_in[9];
    const float* qW4 = (const float*)d_in[10]; const float* qb4 = (const float*)d_in[11];
    const float* dW1 = (const float*)d_in[12]; const float* db1 = (const float*)d_in[13];
    const float* dW2 = (const float*)d_in[14]; const float* db2 = (const float*)d_in[15];
    const float* dW3 = (const float*)d_in[16]; const float* db3 = (const float*)d_in[17];
    const float* dW4 = (const float*)d_in[18]; const float* db4 = (const float*)d_in[19];
    const float* lW1 = (const float*)d_in[20]; const float* lb1 = (const float*)d_in[21];
    const float* lW2 = (const float*)d_in[22]; const float* lb2 = (const float*)d_in[23];
    const float* lW3 = (const float*)d_in[24]; const float* lb3 = (const float*)d_in[25];
    (void)in_sizes; (void)n_in; (void)out_size; (void)ws_size;

    const int* q_src = q_el;  const int* q_dst = q_el + EQ;
    const int* d_src = d_el;  const int* d_dst = d_el + ED;

    // ---- workspace layout ----
    char* wsb = (char*)d_ws;
    size_t off = 0;
    auto alloc = [&](size_t bytes) { void* p = wsb + off; off += (bytes + 255) & ~(size_t)255; return p; };

    unsigned char*  x8d = (unsigned char*)alloc((size_t)ND * FDIM);       // fp8 d_x
    unsigned char*  x8q = (unsigned char*)alloc((size_t)NQ * FDIM);       // adjacent
    unsigned short* dag = (unsigned short*)alloc((size_t)ND * FDIM * 2);  // agg1 out bf16
    unsigned short* qag = (unsigned short*)alloc((size_t)NQ * FDIM * 2);
    unsigned char*  h8d = (unsigned char*)alloc((size_t)ND * HDIM);       // conv1 out fp8
    unsigned char*  h8q = (unsigned char*)alloc((size_t)NQ * HDIM);
    unsigned short* had = (unsigned short*)alloc((size_t)ND * HDIM * 2);  // agg2 out bf16
    unsigned short* haq = (unsigned short*)alloc((size_t)NQ * HDIM * 2);
    float* pooled = (float*)alloc(512 * 4);
    int* d_deg    = (int*)alloc((size_t)ND * 4);
    int* q_deg    = (int*)alloc((size_t)NQ * 4);   // adjacent to d_deg (one memset)
    int* d_rowptr = (int*)alloc((size_t)(ND + 1) * 4);
    int* d_cursor = (int*)alloc((size_t)ND * 4);
    int* d_csrsrc = (int*)alloc((size_t)ED * 4);
    int* d_bsum   = (int*)alloc(256 * 4);
    int* d_boff   = (int*)alloc(256 * 4);
    int* q_rowptr = (int*)alloc((size_t)(NQ + 1) * 4);
    int* q_cursor = (int*)alloc((size_t)NQ * 4);
    int* q_csrsrc = (int*)alloc((size_t)EQ * 4);
    int* q_bsum   = (int*)alloc(256 * 4);
    int* q_boff   = (int*)alloc(256 * 4);
    unsigned short* pdW1 = (unsigned short*)alloc((size_t)FDIM * 256 * 2);
    unsigned short* pdW2 = (unsigned short*)alloc((size_t)HDIM * 256 * 2);
    unsigned short* pdW3 = (unsigned short*)alloc((size_t)HDIM * 256 * 2);
    unsigned short* pdW4 = (unsigned short*)alloc((size_t)HDIM * 256 * 2);
    unsigned short* pqW1 = (unsigned short*)alloc((size_t)FDIM * 256 * 2);
    unsigned short* pqW2 = (unsigned short*)alloc((size_t)HDIM * 256 * 2);
    unsigned short* pqW3 = (unsigned short*)alloc((size_t)HDIM * 256 * 2);
    unsigned short* pqW4 = (unsigned short*)alloc((size_t)HDIM * 256 * 2);

    hipMemsetAsync(pooled, 0, 512 * 4, stream);
    hipMemsetAsync(d_deg, 0, (char*)(q_deg + NQ) - (char*)d_deg, stream);

    // ---- prepass: cvt + pack + count ----
    const int d_eb = (ED + 255) / 256;
    const int q_eb = (EQ + 255) / 256;
    const int d_nb = (ND + 255) / 256;
    const int q_nb = (NQ + 255) / 256;
    {
        PackDesc pd;
        const float* Ws[8] = {dW1, dW2, dW3, dW4, qW1, qW2, qW3, qW4};
        unsigned short* Wps[8] = {pdW1, pdW2, pdW3, pdW4, pqW1, pqW2, pqW3, pqW4};
        int kts[8] = {4, 8, 8, 8, 4, 8, 8, 8};
        int s = 0;
        for (int i = 0; i < 8; ++i) {
            pd.W[i] = Ws[i]; pd.Wp[i] = Wps[i]; pd.KT[i] = kts[i];
            pd.start[i] = s; s += 16 * kts[i];
        }
        pd.start[8] = s;
        const int pack_units = s;
        const int pack_b = (s + 3) / 4;
        long long nd4 = (long long)ND * FDIM / 4;
        long long n4 = nd4 + (long long)NQ * FDIM / 4;
        const int cvt_b = (int)((n4 + 255) / 256);
        prepass<<<cvt_b + pack_b + d_eb + q_eb, 256, 0, stream>>>(
            d_x, q_x, x8d, nd4, n4, cvt_b, pd, pack_units, pack_b,
            d_dst, d_deg, q_dst, q_deg, d_eb);
    }

    // ---- CSR scan + fill ----
    scan_phase1_both<<<d_nb + q_nb, 256, 0, stream>>>(d_deg, d_rowptr, d_bsum,
                                                      q_deg, q_rowptr, q_bsum, d_nb);
    scan_phase2_both<<<2, 256, 0, stream>>>(d_bsum, d_boff, d_rowptr + ND, d_nb,
                                            q_bsum, q_boff, q_rowptr + NQ, q_nb);
    scan_phase3_both<<<d_nb + q_nb, 256, 0, stream>>>(d_rowptr, d_boff, d_cursor,
                                                      q_rowptr, q_boff, q_cursor, d_nb);
    fill_csr_both<<<d_eb + q_eb, 256, 0, stream>>>(d_src, d_dst, d_cursor, d_csrsrc,
                                                   q_src, q_dst, q_cursor, q_csrsrc, d_eb);

    // ---- GIN conv 1: fp8 gather agg -> bf16, then wave-tile MLP -> h fp8 ----
    const int ndpair = ND / 2;
    const int qpair = NQ / 2;
    const int ndt = ND / 16;               // 3125 data tiles (exact)
    const int total_tiles = ndt + NQ / 16;  // + 4 query tiles
    const int mlp_blocks = (total_tiles + 3) / 4;  // 783

    gin_agg_f8_128_dual<<<ndpair + qpair, 64, 0, stream>>>(
        x8d, d_rowptr, d_csrsrc, dag, x8q, q_rowptr, q_csrsrc, qag, ndpair);
    mlp_dual<FDIM><<<mlp_blocks, 256, 0, stream>>>(
        dag, pdW1, db1, pdW2, db2, h8d, nullptr, ndt,
        qag, pqW1, qb1, pqW2, qb2, h8q, nullptr, 1, total_tiles);

    // ---- GIN conv 2: fp8 gather agg -> bf16, then wave-tile MLP (pool-only) ----
    gin_agg_f8_256_dual<<<ND + NQ, 64, 0, stream>>>(
        h8d, d_rowptr, d_csrsrc, had, h8q, q_rowptr, q_csrsrc, haq);
    mlp_dual<HDIM><<<mlp_blocks, 256, 0, stream>>>(
        had, pdW3, db3, pdW4, db4, nullptr, pooled + 256, ndt,
        haq, pqW3, qb3, pqW4, qb4, nullptr, pooled, 0, total_tiles);

    // ---- head ----
    mlp_head<<<1, 256, 0, stream>>>(pooled, lW1, lb1, lW2, lb2, lW3, lb3, (float*)d_out);
}

// Round 12
// 256.086 us; speedup vs baseline: 1.5165x; 1.5165x over previous
//
#include <hip/hip_runtime.h>
#include <hip/hip_bf16.h>

// ---------------------------------------------------------------------------
// BasicCountNet round 12:
//   - best-of assembly: R8 mlp structure (64-row, 4 waves, 4 fn/wave, 96 VGPR
//     headroom) + R9 fp8-x conv1 gather (2 nodes/wave).
//   - mlp change: A-staging phase REMOVED; pass1 reads A-fragments directly
//     from global (L2). Doubles overlappable loads per kt (4 A + 4 W vs 4 W),
//     removes stage+barrier from the per-tile serial chain (R11 lesson:
//     mlp time == W/A-load ILP).
// ---------------------------------------------------------------------------

#define NQ 64
#define EQ 512
#define ND 50000
#define ED 600000
#define FDIM 128
#define HDIM 256

typedef __attribute__((ext_vector_type(8))) short short8;
typedef __attribute__((ext_vector_type(4))) float f32x4;
typedef __attribute__((ext_vector_type(2))) float floatx2;
typedef __attribute__((ext_vector_type(4))) unsigned short us4;
typedef __attribute__((ext_vector_type(2))) unsigned short us2;

__device__ __forceinline__ unsigned short f2bf(float f) {
    union { float f; unsigned u; } v; v.f = f;
    unsigned r = v.u + 0x7FFF + ((v.u >> 16) & 1);   // RNE
    return (unsigned short)(r >> 16);
}
__device__ __forceinline__ float bf2f(unsigned short u) {
    union { unsigned u; float f; } v; v.u = ((unsigned)u) << 16;
    return v.f;
}

// ---------------- weight pack descriptor ----------------
// Wp layout: [ct(16)][kt(KT)][lane(64)][j(8)]; elem = W[kt*32+(l>>4)*8+j][ct*16+(l&15)]

struct PackDesc {
    const float* W[8];
    unsigned short* Wp[8];
    int KT[8];
    int start[9];
};

__device__ __forceinline__ void pack_unit(const PackDesc& pd, int unit, int l) {
    int m = 0;
    while (m < 7 && unit >= pd.start[m + 1]) ++m;
    const int local = unit - pd.start[m];
    const int KT = pd.KT[m];
    const int kt = local % KT;
    const int ct = local / KT;
    const float* W = pd.W[m];
    unsigned short* Wp = pd.Wp[m];
    const int row = kt * 32 + (l >> 4) * 8;
    const int col = ct * 16 + (l & 15);
    short8 v;
#pragma unroll
    for (int j = 0; j < 8; ++j) v[j] = (short)f2bf(W[(size_t)(row + j) * 256 + col]);
    *(short8*)(Wp + (((size_t)(ct * KT + kt)) * 64 + l) * 8) = v;
}

// ---------------- prepass: cvt(x->fp8) + pack weights + count degrees ----------------

__global__ void prepass(const float* __restrict__ xd, const float* __restrict__ xq,
                        unsigned char* __restrict__ x8, long long nd4, long long n4,
                        int cvt_b, PackDesc pd, int pack_units, int pack_b,
                        const int* __restrict__ d_dst, int* __restrict__ d_deg,
                        const int* __restrict__ q_dst, int* __restrict__ q_deg,
                        int d_eb) {
    const int b = blockIdx.x;
    const int tid = threadIdx.x;
    if (b < cvt_b) {
        long long i = (long long)b * 256 + tid;
        if (i >= n4) return;
        const float* src = (i < nd4) ? (xd + i * 4) : (xq + (i - nd4) * 4);
        float4 v = *(const float4*)src;
        int p = __builtin_amdgcn_cvt_pk_fp8_f32(v.x, v.y, 0, false);
        p = __builtin_amdgcn_cvt_pk_fp8_f32(v.z, v.w, p, true);
        *(unsigned*)(x8 + i * 4) = (unsigned)p;
    } else if (b < cvt_b + pack_b) {
        const int unit = (b - cvt_b) * 4 + (tid >> 6);
        if (unit < pack_units) pack_unit(pd, unit, tid & 63);
    } else {
        const int cb = b - cvt_b - pack_b;
        if (cb < d_eb) {
            int e = cb * 256 + tid;
            if (e < ED) atomicAdd(&d_deg[d_dst[e]], 1);
        } else {
            int e = (cb - d_eb) * 256 + tid;
            if (e < EQ) atomicAdd(&q_deg[q_dst[e]], 1);
        }
    }
}

// ---------------- CSR scan/fill (dual) ----------------

__device__ __forceinline__ void scan1_body(const int* deg, int* rowptr, int* bsum,
                                           int n, int blk) {
    __shared__ int sh[256];
    const int t = threadIdx.x;
    const int i = blk * 256 + t;
    const int v = (i < n) ? deg[i] : 0;
    sh[t] = v;
    __syncthreads();
    for (int off = 1; off < 256; off <<= 1) {
        int x = (t >= off) ? sh[t - off] : 0;
        __syncthreads();
        sh[t] += x;
        __syncthreads();
    }
    if (i < n) rowptr[i] = sh[t] - v;
    if (t == 255) bsum[blk] = sh[255];
}

__global__ void scan_phase1_both(const int* __restrict__ d_deg, int* __restrict__ d_rowptr,
                                 int* __restrict__ d_bsum,
                                 const int* __restrict__ q_deg, int* __restrict__ q_rowptr,
                                 int* __restrict__ q_bsum, int dblocks) {
    int b = blockIdx.x;
    if (b < dblocks) scan1_body(d_deg, d_rowptr, d_bsum, ND, b);
    else             scan1_body(q_deg, q_rowptr, q_bsum, NQ, b - dblocks);
}

__device__ __forceinline__ void scan2_body(const int* bsum, int* boff, int* rowptr_n, int nb) {
    __shared__ int sh[256];
    const int t = threadIdx.x;
    const int v = (t < nb) ? bsum[t] : 0;
    sh[t] = v;
    __syncthreads();
    for (int off = 1; off < 256; off <<= 1) {
        int x = (t >= off) ? sh[t - off] : 0;
        __syncthreads();
        sh[t] += x;
        __syncthreads();
    }
    if (t < nb) boff[t] = sh[t] - v;
    if (t == 255) *rowptr_n = sh[255];
}

__global__ void scan_phase2_both(const int* __restrict__ d_bsum, int* __restrict__ d_boff,
                                 int* __restrict__ d_rowptr_n, int d_nb,
                                 const int* __restrict__ q_bsum, int* __restrict__ q_boff,
                                 int* __restrict__ q_rowptr_n, int q_nb) {
    if (blockIdx.x == 0) scan2_body(d_bsum, d_boff, d_rowptr_n, d_nb);
    else                 scan2_body(q_bsum, q_boff, q_rowptr_n, q_nb);
}

__global__ void scan_phase3_both(int* __restrict__ d_rowptr, const int* __restrict__ d_boff,
                                 int* __restrict__ d_cursor,
                                 int* __restrict__ q_rowptr, const int* __restrict__ q_boff,
                                 int* __restrict__ q_cursor, int dblocks) {
    int b = blockIdx.x;
    if (b < dblocks) {
        int i = b * 256 + threadIdx.x;
        if (i < ND) {
            int r = d_rowptr[i] + d_boff[b];
            d_rowptr[i] = r; d_cursor[i] = r;
        }
    } else {
        int i = (b - dblocks) * 256 + threadIdx.x;
        if (i < NQ) {
            int r = q_rowptr[i] + q_boff[b - dblocks];
            q_rowptr[i] = r; q_cursor[i] = r;
        }
    }
}

__global__ void fill_csr_both(const int* __restrict__ d_src, const int* __restrict__ d_dst,
                              int* __restrict__ d_cursor, int* __restrict__ d_csrsrc,
                              const int* __restrict__ q_src, const int* __restrict__ q_dst,
                              int* __restrict__ q_cursor, int* __restrict__ q_csrsrc,
                              int dblocks) {
    int b = blockIdx.x;
    if (b < dblocks) {
        int e = b * 256 + threadIdx.x;
        if (e < ED) {
            int p = atomicAdd(&d_cursor[d_dst[e]], 1);
            d_csrsrc[p] = d_src[e];
        }
    } else {
        int e = (b - dblocks) * 256 + threadIdx.x;
        if (e < EQ) {
            int p = atomicAdd(&q_cursor[q_dst[e]], 1);
            q_csrsrc[p] = q_src[e];
        }
    }
}

// ---------------- agg conv1: fp8 in (128B rows) / bf16 out, 2 nodes per wave ----------------

__global__ void gin_agg_f8_128_dual(const unsigned char* __restrict__ xd,
                                    const int* __restrict__ rpd, const int* __restrict__ csd,
                                    unsigned short* __restrict__ od,
                                    const unsigned char* __restrict__ xq,
                                    const int* __restrict__ rpq, const int* __restrict__ csq,
                                    unsigned short* __restrict__ oq, int ndpair) {
    const unsigned char* x; const int* rowptr; const int* csr; unsigned short* out; int nb;
    if ((int)blockIdx.x < ndpair) { x = xd; rowptr = rpd; csr = csd; out = od; nb = blockIdx.x; }
    else { x = xq; rowptr = rpq; csr = csq; out = oq; nb = blockIdx.x - ndpair; }

    const int t = threadIdx.x;
    const int node = nb * 2 + (t >> 5);
    const int c = t & 31;

    const int beg = rowptr[node];
    const int end = rowptr[node + 1];

    float a0, a1, a2, a3;
    {
        const unsigned w = *(const unsigned*)(x + (size_t)node * 128 + c * 4);
        floatx2 lo = __builtin_amdgcn_cvt_pk_f32_fp8((int)w, false);
        floatx2 hi = __builtin_amdgcn_cvt_pk_f32_fp8((int)w, true);
        a0 = lo[0]; a1 = lo[1]; a2 = hi[0]; a3 = hi[1];
    }
    for (int j = beg; j < end; ++j) {
        const unsigned w = *(const unsigned*)(x + (size_t)csr[j] * 128 + c * 4);
        floatx2 lo = __builtin_amdgcn_cvt_pk_f32_fp8((int)w, false);
        floatx2 hi = __builtin_amdgcn_cvt_pk_f32_fp8((int)w, true);
        a0 += lo[0]; a1 += lo[1]; a2 += hi[0]; a3 += hi[1];
    }
    us4 r;
    r[0] = f2bf(a0); r[1] = f2bf(a1); r[2] = f2bf(a2); r[3] = f2bf(a3);
    *(us4*)(out + (size_t)node * 128 + c * 4) = r;
}

// ---------------- agg conv2: fp8 in (256B rows) / bf16 out, 1 node per wave ----------------

__global__ void gin_agg_f8_256_dual(const unsigned char* __restrict__ xd,
                                    const int* __restrict__ rpd, const int* __restrict__ csd,
                                    unsigned short* __restrict__ od,
                                    const unsigned char* __restrict__ xq,
                                    const int* __restrict__ rpq, const int* __restrict__ csq,
                                    unsigned short* __restrict__ oq) {
    const unsigned char* x; const int* rowptr; const int* csr; unsigned short* out; int node;
    if ((int)blockIdx.x < ND) { x = xd; rowptr = rpd; csr = csd; out = od; node = blockIdx.x; }
    else { x = xq; rowptr = rpq; csr = csq; out = oq; node = blockIdx.x - ND; }

    const int t = threadIdx.x;
    const int beg = rowptr[node];
    const int end = rowptr[node + 1];

    float a0, a1, a2, a3;
    {
        const unsigned w = *(const unsigned*)(x + (size_t)node * 256 + t * 4);
        floatx2 lo = __builtin_amdgcn_cvt_pk_f32_fp8((int)w, false);
        floatx2 hi = __builtin_amdgcn_cvt_pk_f32_fp8((int)w, true);
        a0 = lo[0]; a1 = lo[1]; a2 = hi[0]; a3 = hi[1];
    }
    int j = beg;
    for (; j + 1 < end; j += 2) {
        const unsigned w0 = *(const unsigned*)(x + (size_t)csr[j] * 256 + t * 4);
        const unsigned w1 = *(const unsigned*)(x + (size_t)csr[j + 1] * 256 + t * 4);
        floatx2 l0 = __builtin_amdgcn_cvt_pk_f32_fp8((int)w0, false);
        floatx2 h0 = __builtin_amdgcn_cvt_pk_f32_fp8((int)w0, true);
        floatx2 l1 = __builtin_amdgcn_cvt_pk_f32_fp8((int)w1, false);
        floatx2 h1 = __builtin_amdgcn_cvt_pk_f32_fp8((int)w1, true);
        a0 += l0[0] + l1[0]; a1 += l0[1] + l1[1];
        a2 += h0[0] + h1[0]; a3 += h0[1] + h1[1];
    }
    if (j < end) {
        const unsigned w0 = *(const unsigned*)(x + (size_t)csr[j] * 256 + t * 4);
        floatx2 l0 = __builtin_amdgcn_cvt_pk_f32_fp8((int)w0, false);
        floatx2 h0 = __builtin_amdgcn_cvt_pk_f32_fp8((int)w0, true);
        a0 += l0[0]; a1 += l0[1]; a2 += h0[0]; a3 += h0[1];
    }
    us4 r;
    r[0] = f2bf(a0); r[1] = f2bf(a1); r[2] = f2bf(a2); r[3] = f2bf(a3);
    *(us4*)(out + (size_t)node * 256 + t * 4) = r;
}

// ---------------- fused MLP: 64 rows x 256 cols, 4 waves, NO A-staging ----------------
// pass1 reads A-fragments directly from global (L2); T1 LDS round-trip; pass2;
// fp8 store / pool. Dual: data blocks [0,ndb), query block ndb.

template <int KIN>
__global__ __launch_bounds__(256) void mlp_dual(
    const unsigned short* __restrict__ Ad,
    const unsigned short* __restrict__ W1pd, const float* __restrict__ b1d,
    const unsigned short* __restrict__ W2pd, const float* __restrict__ b2d,
    unsigned char* __restrict__ C8d, float* __restrict__ poold, int ndb,
    const unsigned short* __restrict__ Aq,
    const unsigned short* __restrict__ W1pq, const float* __restrict__ b1q,
    const unsigned short* __restrict__ W2pq, const float* __restrict__ b2q,
    unsigned char* __restrict__ C8q, float* __restrict__ poolq,
    int relu_out) {
    constexpr int KT1 = KIN / 32;
    __shared__ __align__(16) unsigned short lds[64 * 256];  // 32 KB: T1 only

    const unsigned short* A; const unsigned short* W1p; const float* b1;
    const unsigned short* W2p; const float* b2;
    unsigned char* C8; float* pool; int row0, N;
    if ((int)blockIdx.x < ndb) {
        A = Ad; W1p = W1pd; b1 = b1d; W2p = W2pd; b2 = b2d;
        C8 = C8d; pool = poold; row0 = blockIdx.x * 64; N = ND;
    } else {
        A = Aq; W1p = W1pq; b1 = b1q; W2p = W2pq; b2 = b2q;
        C8 = C8q; pool = poolq; row0 = 0; N = NQ;
    }

    const int tid = threadIdx.x;
    const int lane = tid & 63;
    const int wv = tid >> 6;
    const int lrow = lane & 15;
    const int lk2 = (lane >> 4) * 8;

    // ---- pass 1: T1 = relu(A @ W1 + b1), A-fragments straight from global ----
    f32x4 acc1[4][4];
#pragma unroll
    for (int fm = 0; fm < 4; ++fm)
#pragma unroll
        for (int fn = 0; fn < 4; ++fn) acc1[fm][fn] = (f32x4)(0.f);

    const unsigned short* W1Base = W1p + ((size_t)(wv * 4) * KT1 * 64 + lane) * 8;
    // per-lane A base for its fragment rows (row = row0 + fm*16 + lrow)
    const unsigned short* Alane = A + (size_t)(row0 + lrow) * KIN + lk2;

#pragma unroll
    for (int kt = 0; kt < KT1; ++kt) {
        short8 a[4], bf[4];
#pragma unroll
        for (int fm = 0; fm < 4; ++fm)
            a[fm] = *(const short8*)(Alane + (size_t)(fm * 16) * KIN + kt * 32);
#pragma unroll
        for (int fn = 0; fn < 4; ++fn)
            bf[fn] = *(const short8*)(W1Base + ((size_t)fn * KT1 + kt) * 64 * 8);
#pragma unroll
        for (int fm = 0; fm < 4; ++fm)
#pragma unroll
            for (int fn = 0; fn < 4; ++fn)
                acc1[fm][fn] = __builtin_amdgcn_mfma_f32_16x16x32_bf16(
                    a[fm], bf[fn], acc1[fm][fn], 0, 0, 0);
    }

    // ---- T1 tile (bias + relu, bf16) into lds, stride 256, XOR swizzle ----
#pragma unroll
    for (int fn = 0; fn < 4; ++fn) {
        const int col = wv * 64 + fn * 16 + lrow;
        const float bv = b1[col];
#pragma unroll
        for (int fm = 0; fm < 4; ++fm) {
            const int rbase = fm * 16 + (lane >> 4) * 4;
#pragma unroll
            for (int r = 0; r < 4; ++r) {
                const int row = rbase + r;
                const float v = fmaxf(acc1[fm][fn][r] + bv, 0.f);
                unsigned byte = (unsigned)((row * 256 + col) * 2) ^ (unsigned)((row & 7) << 4);
                *(unsigned short*)((char*)lds + byte) = f2bf(v);
            }
        }
    }
    __syncthreads();

    // ---- pass 2: out = T1 @ W2 + b2 ----
    f32x4 acc2[4][4];
#pragma unroll
    for (int fm = 0; fm < 4; ++fm)
#pragma unroll
        for (int fn = 0; fn < 4; ++fn) acc2[fm][fn] = (f32x4)(0.f);

    const unsigned short* W2Base = W2p + ((size_t)(wv * 4) * 8 * 64 + lane) * 8;
#pragma unroll
    for (int kt = 0; kt < 8; ++kt) {
        short8 a[4], bf[4];
#pragma unroll
        for (int fm = 0; fm < 4; ++fm) {
            const int r = fm * 16 + lrow;
            unsigned byte = (unsigned)((r * 256 + kt * 32 + lk2) * 2) ^ (unsigned)((r & 7) << 4);
            a[fm] = *(const short8*)((const char*)lds + byte);
        }
#pragma unroll
        for (int fn = 0; fn < 4; ++fn)
            bf[fn] = *(const short8*)(W2Base + ((size_t)fn * 8 + kt) * 64 * 8);
#pragma unroll
        for (int fm = 0; fm < 4; ++fm)
#pragma unroll
            for (int fn = 0; fn < 4; ++fn)
                acc2[fm][fn] = __builtin_amdgcn_mfma_f32_16x16x32_bf16(
                    a[fm], bf[fn], acc2[fm][fn], 0, 0, 0);
    }

    // ---- epilogue: bias2 (+relu_out), store fp8 C8 / pool colsum ----
#pragma unroll
    for (int fn = 0; fn < 4; ++fn) {
        const int col = wv * 64 + fn * 16 + lrow;
        const float bv = b2[col];
        float ps = 0.f;
#pragma unroll
        for (int fm = 0; fm < 4; ++fm) {
            const int rbase = row0 + fm * 16 + (lane >> 4) * 4;
#pragma unroll
            for (int r = 0; r < 4; ++r) {
                const int row = rbase + r;
                if (row < N) {
                    float v = acc2[fm][fn][r] + bv;
                    if (relu_out) v = fmaxf(v, 0.f);
                    if (C8) {
                        unsigned p = (unsigned)__builtin_amdgcn_cvt_pk_fp8_f32(v, v, 0, false);
                        C8[(size_t)row * 256 + col] = (unsigned char)(p & 0xff);
                    }
                    ps += v;
                }
            }
        }
        if (pool) {
            ps += __shfl_xor(ps, 16);
            ps += __shfl_xor(ps, 32);
            if ((lane >> 4) == 0) atomicAdd(&pool[col], ps);
        }
    }
}

// ---------------- head ----------------

__global__ void mlp_head(const float* __restrict__ pooled,
                         const float* __restrict__ lW1, const float* __restrict__ lb1,
                         const float* __restrict__ lW2, const float* __restrict__ lb2,
                         const float* __restrict__ lW3, const float* __restrict__ lb3,
                         float* __restrict__ out) {
    __shared__ float h0[512];
    __shared__ float h1[256];
    __shared__ float h2[128];
    const int t = threadIdx.x;  // 256 threads
    h0[t] = pooled[t];
    h0[t + 256] = pooled[t + 256];
    __syncthreads();

    float acc = lb1[t];
    for (int k = 0; k < 512; ++k) acc += h0[k] * lW1[k * 256 + t];
    h1[t] = fmaxf(acc, 0.f);
    __syncthreads();

    if (t < 128) {
        float a = lb2[t];
        for (int k = 0; k < 256; ++k) a += h1[k] * lW2[k * 128 + t];
        h2[t] = fmaxf(a, 0.f);
    }
    __syncthreads();

    if (t < 8) {
        float a = lb3[t];
        for (int k = 0; k < 128; ++k) a += h2[k] * lW3[k * 8 + t];
        out[t] = fmaxf(a, 0.f);
    }
}

// ---------------------------------------------------------------------------

extern "C" void kernel_launch(void* const* d_in, const int* in_sizes, int n_in,
                              void* d_out, int out_size, void* d_ws, size_t ws_size,
                              hipStream_t stream) {
    const float* q_x  = (const float*)d_in[0];
    const float* d_x  = (const float*)d_in[1];
    const int*   q_el = (const int*)d_in[2];
    const int*   d_el = (const int*)d_in[3];
    const float* qW1 = (const float*)d_in[4];  const float* qb1 = (const float*)d_in[5];
    const float* qW2 = (const float*)d_in[6];  const float* qb2 = (const float*)d_in[7];
    const float* qW3 = (const float*)d_in[8];  const float* qb3 = (const float*)d_in[9];
    const float* qW4 = (const float*)d_in[10]; const float* qb4 = (const float*)d_in[11];
    const float* dW1 = (const float*)d_in[12]; const float* db1 = (const float*)d_in[13];
    const float* dW2 = (const float*)d_in[14]; const float* db2 = (const float*)d_in[15];
    const float* dW3 = (const float*)d_in[16]; const float* db3 = (const float*)d_in[17];
    const float* dW4 = (const float*)d_in[18]; const float* db4 = (const float*)d_in[19];
    const float* lW1 = (const float*)d_in[20]; const float* lb1 = (const float*)d_in[21];
    const float* lW2 = (const float*)d_in[22]; const float* lb2 = (const float*)d_in[23];
    const float* lW3 = (const float*)d_in[24]; const float* lb3 = (const float*)d_in[25];
    (void)in_sizes; (void)n_in; (void)out_size; (void)ws_size;

    const int* q_src = q_el;  const int* q_dst = q_el + EQ;
    const int* d_src = d_el;  const int* d_dst = d_el + ED;

    // ---- workspace layout ----
    char* wsb = (char*)d_ws;
    size_t off = 0;
    auto alloc = [&](size_t bytes) { void* p = wsb + off; off += (bytes + 255) & ~(size_t)255; return p; };

    unsigned char*  x8d = (unsigned char*)alloc((size_t)ND * FDIM);       // fp8 d_x
    unsigned char*  x8q = (unsigned char*)alloc((size_t)NQ * FDIM);       // adjacent
    unsigned short* dag = (unsigned short*)alloc((size_t)ND * FDIM * 2);  // agg1 out bf16
    unsigned short* qag = (unsigned short*)alloc((size_t)(NQ + 64) * FDIM * 2);  // +tail pad
    unsigned char*  h8d = (unsigned char*)alloc((size_t)ND * HDIM);       // conv1 out fp8
    unsigned char*  h8q = (unsigned char*)alloc((size_t)NQ * HDIM);
    unsigned short* had = (unsigned short*)alloc((size_t)ND * HDIM * 2);  // agg2 out bf16
    unsigned short* haq = (unsigned short*)alloc((size_t)(NQ + 64) * HDIM * 2);  // +tail pad
    float* pooled = (float*)alloc(512 * 4);
    int* d_deg    = (int*)alloc((size_t)ND * 4);
    int* q_deg    = (int*)alloc((size_t)NQ * 4);   // adjacent to d_deg (one memset)
    int* d_rowptr = (int*)alloc((size_t)(ND + 1) * 4);
    int* d_cursor = (int*)alloc((size_t)ND * 4);
    int* d_csrsrc = (int*)alloc((size_t)ED * 4);
    int* d_bsum   = (int*)alloc(256 * 4);
    int* d_boff   = (int*)alloc(256 * 4);
    int* q_rowptr = (int*)alloc((size_t)(NQ + 1) * 4);
    int* q_cursor = (int*)alloc((size_t)NQ * 4);
    int* q_csrsrc = (int*)alloc((size_t)EQ * 4);
    int* q_bsum   = (int*)alloc(256 * 4);
    int* q_boff   = (int*)alloc(256 * 4);
    unsigned short* pdW1 = (unsigned short*)alloc((size_t)FDIM * 256 * 2);
    unsigned short* pdW2 = (unsigned short*)alloc((size_t)HDIM * 256 * 2);
    unsigned short* pdW3 = (unsigned short*)alloc((size_t)HDIM * 256 * 2);
    unsigned short* pdW4 = (unsigned short*)alloc((size_t)HDIM * 256 * 2);
    unsigned short* pqW1 = (unsigned short*)alloc((size_t)FDIM * 256 * 2);
    unsigned short* pqW2 = (unsigned short*)alloc((size_t)HDIM * 256 * 2);
    unsigned short* pqW3 = (unsigned short*)alloc((size_t)HDIM * 256 * 2);
    unsigned short* pqW4 = (unsigned short*)alloc((size_t)HDIM * 256 * 2);

    hipMemsetAsync(pooled, 0, 512 * 4, stream);
    hipMemsetAsync(d_deg, 0, (char*)(q_deg + NQ) - (char*)d_deg, stream);

    // ---- prepass: cvt + pack + count ----
    const int d_eb = (ED + 255) / 256;
    const int q_eb = (EQ + 255) / 256;
    const int d_nb = (ND + 255) / 256;
    const int q_nb = (NQ + 255) / 256;
    {
        PackDesc pd;
        const float* Ws[8] = {dW1, dW2, dW3, dW4, qW1, qW2, qW3, qW4};
        unsigned short* Wps[8] = {pdW1, pdW2, pdW3, pdW4, pqW1, pqW2, pqW3, pqW4};
        int kts[8] = {4, 8, 8, 8, 4, 8, 8, 8};
        int s = 0;
        for (int i = 0; i < 8; ++i) {
            pd.W[i] = Ws[i]; pd.Wp[i] = Wps[i]; pd.KT[i] = kts[i];
            pd.start[i] = s; s += 16 * kts[i];
        }
        pd.start[8] = s;
        const int pack_units = s;
        const int pack_b = (s + 3) / 4;
        long long nd4 = (long long)ND * FDIM / 4;
        long long n4 = nd4 + (long long)NQ * FDIM / 4;
        const int cvt_b = (int)((n4 + 255) / 256);
        prepass<<<cvt_b + pack_b + d_eb + q_eb, 256, 0, stream>>>(
            d_x, q_x, x8d, nd4, n4, cvt_b, pd, pack_units, pack_b,
            d_dst, d_deg, q_dst, q_deg, d_eb);
    }

    // ---- CSR scan + fill ----
    scan_phase1_both<<<d_nb + q_nb, 256, 0, stream>>>(d_deg, d_rowptr, d_bsum,
                                                      q_deg, q_rowptr, q_bsum, d_nb);
    scan_phase2_both<<<2, 256, 0, stream>>>(d_bsum, d_boff, d_rowptr + ND, d_nb,
                                            q_bsum, q_boff, q_rowptr + NQ, q_nb);
    scan_phase3_both<<<d_nb + q_nb, 256, 0, stream>>>(d_rowptr, d_boff, d_cursor,
                                                      q_rowptr, q_boff, q_cursor, d_nb);
    fill_csr_both<<<d_eb + q_eb, 256, 0, stream>>>(d_src, d_dst, d_cursor, d_csrsrc,
                                                   q_src, q_dst, q_cursor, q_csrsrc, d_eb);

    // ---- GIN conv 1: fp8 gather agg -> bf16, then MLP (no-stage) -> h fp8 ----
    const int ndpair = ND / 2;
    const int qpair = NQ / 2;
    const int ndb = (ND + 63) / 64;  // 782

    gin_agg_f8_128_dual<<<ndpair + qpair, 64, 0, stream>>>(
        x8d, d_rowptr, d_csrsrc, dag, x8q, q_rowptr, q_csrsrc, qag, ndpair);
    mlp_dual<FDIM><<<ndb + 1, 256, 0, stream>>>(
        dag, pdW1, db1, pdW2, db2, h8d, nullptr, ndb,
        qag, pqW1, qb1, pqW2, qb2, h8q, nullptr, 1);

    // ---- GIN conv 2: fp8 gather agg -> bf16, then MLP (pool-only) ----
    gin_agg_f8_256_dual<<<ND + NQ, 64, 0, stream>>>(
        h8d, d_rowptr, d_csrsrc, had, h8q, q_rowptr, q_csrsrc, haq);
    mlp_dual<HDIM><<<ndb + 1, 256, 0, stream>>>(
        had, pdW3, db3, pdW4, db4, nullptr, pooled + 256, ndb,
        haq, pqW3, qb3, pqW4, qb4, nullptr, pooled, 0);

    // ---- head ----
    mlp_head<<<1, 256, 0, stream>>>(pooled, lW1, lb1, lW2, lb2, lW3, lb3, (float*)d_out);
}

// Round 13
// 245.044 us; speedup vs baseline: 1.5849x; 1.0451x over previous
//
#include <hip/hip_runtime.h>
#include <hip/hip_bf16.h>

// ---------------------------------------------------------------------------
// BasicCountNet round 13:
//   - R8 baseline (best measured 236us) with ONE change: conv2's MLP second
//     GEMM eliminated algebraically. Final layer has no ReLU before pooling:
//     pool = (sum_rows T1) @ W4 + N*b4. New t1pool kernel = pass1 only
//     (no LDS, no barrier, no W4); exact fp32 W4 matvec folded into head.
// ---------------------------------------------------------------------------

#define NQ 64
#define EQ 512
#define ND 50000
#define ED 600000
#define FDIM 128
#define HDIM 256

typedef __attribute__((ext_vector_type(8))) short short8;
typedef __attribute__((ext_vector_type(4))) float f32x4;
typedef __attribute__((ext_vector_type(2))) float floatx2;
typedef __attribute__((ext_vector_type(4))) unsigned short us4;
typedef __attribute__((ext_vector_type(2))) unsigned short us2;

__device__ __forceinline__ unsigned short f2bf(float f) {
    union { float f; unsigned u; } v; v.f = f;
    unsigned r = v.u + 0x7FFF + ((v.u >> 16) & 1);   // RNE
    return (unsigned short)(r >> 16);
}
__device__ __forceinline__ float bf2f(unsigned short u) {
    union { unsigned u; float f; } v; v.u = ((unsigned)u) << 16;
    return v.f;
}

// ---------------- weight pack descriptor (6 matrices: W1..W3 per graph) ----------------
// Wp layout: [ct(16)][kt(KT)][lane(64)][j(8)]; elem = W[kt*32+(l>>4)*8+j][ct*16+(l&15)]

struct PackDesc {
    const float* W[8];
    unsigned short* Wp[8];
    int KT[8];
    int start[9];
};

__device__ __forceinline__ void pack_unit(const PackDesc& pd, int unit, int l) {
    int m = 0;
    while (m < 7 && unit >= pd.start[m + 1]) ++m;
    const int local = unit - pd.start[m];
    const int KT = pd.KT[m];
    const int kt = local % KT;
    const int ct = local / KT;
    const float* W = pd.W[m];
    unsigned short* Wp = pd.Wp[m];
    const int row = kt * 32 + (l >> 4) * 8;
    const int col = ct * 16 + (l & 15);
    short8 v;
#pragma unroll
    for (int j = 0; j < 8; ++j) v[j] = (short)f2bf(W[(size_t)(row + j) * 256 + col]);
    *(short8*)(Wp + (((size_t)(ct * KT + kt)) * 64 + l) * 8) = v;
}

// ---------------- prepass: cvt(x->bf16) + pack weights + count degrees ----------------

__global__ void prepass(const float* __restrict__ xd, const float* __restrict__ xq,
                        unsigned short* __restrict__ bx, long long nd4, long long n4,
                        int cvt_b, PackDesc pd, int pack_units, int pack_b,
                        const int* __restrict__ d_dst, int* __restrict__ d_deg,
                        const int* __restrict__ q_dst, int* __restrict__ q_deg,
                        int d_eb) {
    const int b = blockIdx.x;
    const int tid = threadIdx.x;
    if (b < cvt_b) {
        long long i = (long long)b * 256 + tid;
        if (i >= n4) return;
        const float* src = (i < nd4) ? (xd + i * 4) : (xq + (i - nd4) * 4);
        float4 v = *(const float4*)src;
        us4 o;
        o[0] = f2bf(v.x); o[1] = f2bf(v.y); o[2] = f2bf(v.z); o[3] = f2bf(v.w);
        *(us4*)(bx + i * 4) = o;
    } else if (b < cvt_b + pack_b) {
        const int unit = (b - cvt_b) * 4 + (tid >> 6);
        if (unit < pack_units) pack_unit(pd, unit, tid & 63);
    } else {
        const int cb = b - cvt_b - pack_b;
        if (cb < d_eb) {
            int e = cb * 256 + tid;
            if (e < ED) atomicAdd(&d_deg[d_dst[e]], 1);
        } else {
            int e = (cb - d_eb) * 256 + tid;
            if (e < EQ) atomicAdd(&q_deg[q_dst[e]], 1);
        }
    }
}

// ---------------- CSR scan/fill (dual) ----------------

__device__ __forceinline__ void scan1_body(const int* deg, int* rowptr, int* bsum,
                                           int n, int blk) {
    __shared__ int sh[256];
    const int t = threadIdx.x;
    const int i = blk * 256 + t;
    const int v = (i < n) ? deg[i] : 0;
    sh[t] = v;
    __syncthreads();
    for (int off = 1; off < 256; off <<= 1) {
        int x = (t >= off) ? sh[t - off] : 0;
        __syncthreads();
        sh[t] += x;
        __syncthreads();
    }
    if (i < n) rowptr[i] = sh[t] - v;
    if (t == 255) bsum[blk] = sh[255];
}

__global__ void scan_phase1_both(const int* __restrict__ d_deg, int* __restrict__ d_rowptr,
                                 int* __restrict__ d_bsum,
                                 const int* __restrict__ q_deg, int* __restrict__ q_rowptr,
                                 int* __restrict__ q_bsum, int dblocks) {
    int b = blockIdx.x;
    if (b < dblocks) scan1_body(d_deg, d_rowptr, d_bsum, ND, b);
    else             scan1_body(q_deg, q_rowptr, q_bsum, NQ, b - dblocks);
}

__device__ __forceinline__ void scan2_body(const int* bsum, int* boff, int* rowptr_n, int nb) {
    __shared__ int sh[256];
    const int t = threadIdx.x;
    const int v = (t < nb) ? bsum[t] : 0;
    sh[t] = v;
    __syncthreads();
    for (int off = 1; off < 256; off <<= 1) {
        int x = (t >= off) ? sh[t - off] : 0;
        __syncthreads();
        sh[t] += x;
        __syncthreads();
    }
    if (t < nb) boff[t] = sh[t] - v;
    if (t == 255) *rowptr_n = sh[255];
}

__global__ void scan_phase2_both(const int* __restrict__ d_bsum, int* __restrict__ d_boff,
                                 int* __restrict__ d_rowptr_n, int d_nb,
                                 const int* __restrict__ q_bsum, int* __restrict__ q_boff,
                                 int* __restrict__ q_rowptr_n, int q_nb) {
    if (blockIdx.x == 0) scan2_body(d_bsum, d_boff, d_rowptr_n, d_nb);
    else                 scan2_body(q_bsum, q_boff, q_rowptr_n, q_nb);
}

__global__ void scan_phase3_both(int* __restrict__ d_rowptr, const int* __restrict__ d_boff,
                                 int* __restrict__ d_cursor,
                                 int* __restrict__ q_rowptr, const int* __restrict__ q_boff,
                                 int* __restrict__ q_cursor, int dblocks) {
    int b = blockIdx.x;
    if (b < dblocks) {
        int i = b * 256 + threadIdx.x;
        if (i < ND) {
            int r = d_rowptr[i] + d_boff[b];
            d_rowptr[i] = r; d_cursor[i] = r;
        }
    } else {
        int i = (b - dblocks) * 256 + threadIdx.x;
        if (i < NQ) {
            int r = q_rowptr[i] + q_boff[b - dblocks];
            q_rowptr[i] = r; q_cursor[i] = r;
        }
    }
}

__global__ void fill_csr_both(const int* __restrict__ d_src, const int* __restrict__ d_dst,
                              int* __restrict__ d_cursor, int* __restrict__ d_csrsrc,
                              const int* __restrict__ q_src, const int* __restrict__ q_dst,
                              int* __restrict__ q_cursor, int* __restrict__ q_csrsrc,
                              int dblocks) {
    int b = blockIdx.x;
    if (b < dblocks) {
        int e = b * 256 + threadIdx.x;
        if (e < ED) {
            int p = atomicAdd(&d_cursor[d_dst[e]], 1);
            d_csrsrc[p] = d_src[e];
        }
    } else {
        int e = (b - dblocks) * 256 + threadIdx.x;
        if (e < EQ) {
            int p = atomicAdd(&q_cursor[q_dst[e]], 1);
            q_csrsrc[p] = q_src[e];
        }
    }
}

// ---------------- aggregation, bf16 in / bf16 out (conv1) ----------------

template <int F>
__global__ void gin_agg_dual(const unsigned short* __restrict__ xd, const int* __restrict__ rpd,
                             const int* __restrict__ csd, unsigned short* __restrict__ od,
                             const unsigned short* __restrict__ xq, const int* __restrict__ rpq,
                             const int* __restrict__ csq, unsigned short* __restrict__ oq) {
    constexpr int V = F / 64;
    const unsigned short* x; const int* rowptr; const int* csr; unsigned short* out; int node;
    if ((int)blockIdx.x < ND) { x = xd; rowptr = rpd; csr = csd; out = od; node = blockIdx.x; }
    else { x = xq; rowptr = rpq; csr = csq; out = oq; node = blockIdx.x - ND; }

    const int t = threadIdx.x;
    const int beg = rowptr[node];
    const int end = rowptr[node + 1];

    float acc[V];
    {
        const unsigned short* p = x + (size_t)node * F + t * V;
        if constexpr (V == 4) {
            us4 v = *(const us4*)p;
#pragma unroll
            for (int i = 0; i < 4; ++i) acc[i] = bf2f(v[i]);
        } else {
            us2 v = *(const us2*)p;
            acc[0] = bf2f(v[0]); acc[1] = bf2f(v[1]);
        }
    }
    int j = beg;
    for (; j + 1 < end; j += 2) {
        const unsigned short* p0 = x + (size_t)csr[j] * F + t * V;
        const unsigned short* p1 = x + (size_t)csr[j + 1] * F + t * V;
        if constexpr (V == 4) {
            us4 v0 = *(const us4*)p0;
            us4 v1 = *(const us4*)p1;
#pragma unroll
            for (int i = 0; i < 4; ++i) acc[i] += bf2f(v0[i]) + bf2f(v1[i]);
        } else {
            us2 v0 = *(const us2*)p0;
            us2 v1 = *(const us2*)p1;
            acc[0] += bf2f(v0[0]) + bf2f(v1[0]);
            acc[1] += bf2f(v0[1]) + bf2f(v1[1]);
        }
    }
    if (j < end) {
        const unsigned short* p0 = x + (size_t)csr[j] * F + t * V;
        if constexpr (V == 4) {
            us4 v0 = *(const us4*)p0;
#pragma unroll
            for (int i = 0; i < 4; ++i) acc[i] += bf2f(v0[i]);
        } else {
            us2 v0 = *(const us2*)p0;
            acc[0] += bf2f(v0[0]); acc[1] += bf2f(v0[1]);
        }
    }
    unsigned short* po = out + (size_t)node * F + t * V;
    if constexpr (V == 4) {
        us4 r;
#pragma unroll
        for (int i = 0; i < 4; ++i) r[i] = f2bf(acc[i]);
        *(us4*)po = r;
    } else {
        us2 r; r[0] = f2bf(acc[0]); r[1] = f2bf(acc[1]);
        *(us2*)po = r;
    }
}

// ---------------- aggregation, fp8 in (256B rows) / bf16 out (conv2) ----------------

__global__ void gin_agg_f8_256_dual(const unsigned char* __restrict__ xd,
                                    const int* __restrict__ rpd, const int* __restrict__ csd,
                                    unsigned short* __restrict__ od,
                                    const unsigned char* __restrict__ xq,
                                    const int* __restrict__ rpq, const int* __restrict__ csq,
                                    unsigned short* __restrict__ oq) {
    const unsigned char* x; const int* rowptr; const int* csr; unsigned short* out; int node;
    if ((int)blockIdx.x < ND) { x = xd; rowptr = rpd; csr = csd; out = od; node = blockIdx.x; }
    else { x = xq; rowptr = rpq; csr = csq; out = oq; node = blockIdx.x - ND; }

    const int t = threadIdx.x;
    const int beg = rowptr[node];
    const int end = rowptr[node + 1];

    float a0, a1, a2, a3;
    {
        const unsigned w = *(const unsigned*)(x + (size_t)node * 256 + t * 4);
        floatx2 lo = __builtin_amdgcn_cvt_pk_f32_fp8((int)w, false);
        floatx2 hi = __builtin_amdgcn_cvt_pk_f32_fp8((int)w, true);
        a0 = lo[0]; a1 = lo[1]; a2 = hi[0]; a3 = hi[1];
    }
    int j = beg;
    for (; j + 1 < end; j += 2) {
        const unsigned w0 = *(const unsigned*)(x + (size_t)csr[j] * 256 + t * 4);
        const unsigned w1 = *(const unsigned*)(x + (size_t)csr[j + 1] * 256 + t * 4);
        floatx2 l0 = __builtin_amdgcn_cvt_pk_f32_fp8((int)w0, false);
        floatx2 h0 = __builtin_amdgcn_cvt_pk_f32_fp8((int)w0, true);
        floatx2 l1 = __builtin_amdgcn_cvt_pk_f32_fp8((int)w1, false);
        floatx2 h1 = __builtin_amdgcn_cvt_pk_f32_fp8((int)w1, true);
        a0 += l0[0] + l1[0]; a1 += l0[1] + l1[1];
        a2 += h0[0] + h1[0]; a3 += h0[1] + h1[1];
    }
    if (j < end) {
        const unsigned w0 = *(const unsigned*)(x + (size_t)csr[j] * 256 + t * 4);
        floatx2 l0 = __builtin_amdgcn_cvt_pk_f32_fp8((int)w0, false);
        floatx2 h0 = __builtin_amdgcn_cvt_pk_f32_fp8((int)w0, true);
        a0 += l0[0]; a1 += l0[1]; a2 += h0[0]; a3 += h0[1];
    }
    us4 r;
    r[0] = f2bf(a0); r[1] = f2bf(a1); r[2] = f2bf(a2); r[3] = f2bf(a3);
    *(us4*)(out + (size_t)node * 256 + t * 4) = r;
}

// ---------------- conv1 MLP (R8): staged A, pass1+T1+pass2, fp8 C out ----------------

template <int KIN>
__global__ __launch_bounds__(256) void mlp_dual(
    const unsigned short* __restrict__ Ad,
    const unsigned short* __restrict__ W1pd, const float* __restrict__ b1d,
    const unsigned short* __restrict__ W2pd, const float* __restrict__ b2d,
    unsigned char* __restrict__ C8d, int ndb,
    const unsigned short* __restrict__ Aq,
    const unsigned short* __restrict__ W1pq, const float* __restrict__ b1q,
    const unsigned short* __restrict__ W2pq, const float* __restrict__ b2q,
    unsigned char* __restrict__ C8q) {
    constexpr int KT1 = KIN / 32;
    __shared__ __align__(16) unsigned short lds[64 * 256];

    const unsigned short* A; const unsigned short* W1p; const float* b1;
    const unsigned short* W2p; const float* b2;
    unsigned char* C8; int row0, N;
    if ((int)blockIdx.x < ndb) {
        A = Ad; W1p = W1pd; b1 = b1d; W2p = W2pd; b2 = b2d;
        C8 = C8d; row0 = blockIdx.x * 64; N = ND;
    } else {
        A = Aq; W1p = W1pq; b1 = b1q; W2p = W2pq; b2 = b2q;
        C8 = C8q; row0 = 0; N = NQ;
    }

    const int tid = threadIdx.x;
    const int lane = tid & 63;
    const int wv = tid >> 6;
    const int lrow = lane & 15;
    const int lk2 = (lane >> 4) * 8;
    const int nrows = (N - row0 < 64) ? (N - row0) : 64;

    for (int idx = tid; idx < nrows * (KIN / 8); idx += 256) {
        const int r = idx / (KIN / 8);
        const int k8 = (idx % (KIN / 8)) * 8;
        short8 v = *(const short8*)(A + (size_t)(row0 + r) * KIN + k8);
        unsigned byte = (unsigned)((r * KIN + k8) * 2) ^ (unsigned)((r & 7) << 4);
        *(short8*)((char*)lds + byte) = v;
    }
    __syncthreads();

    f32x4 acc1[4][4];
#pragma unroll
    for (int fm = 0; fm < 4; ++fm)
#pragma unroll
        for (int fn = 0; fn < 4; ++fn) acc1[fm][fn] = (f32x4)(0.f);

    const unsigned short* W1Base = W1p + ((size_t)(wv * 4) * KT1 * 64 + lane) * 8;
    for (int kt = 0; kt < KT1; ++kt) {
        short8 a[4], bf[4];
#pragma unroll
        for (int fm = 0; fm < 4; ++fm) {
            const int r = fm * 16 + lrow;
            unsigned byte = (unsigned)((r * KIN + kt * 32 + lk2) * 2) ^ (unsigned)((r & 7) << 4);
            a[fm] = *(const short8*)((const char*)lds + byte);
        }
#pragma unroll
        for (int fn = 0; fn < 4; ++fn)
            bf[fn] = *(const short8*)(W1Base + ((size_t)fn * KT1 + kt) * 64 * 8);
#pragma unroll
        for (int fm = 0; fm < 4; ++fm)
#pragma unroll
            for (int fn = 0; fn < 4; ++fn)
                acc1[fm][fn] = __builtin_amdgcn_mfma_f32_16x16x32_bf16(
                    a[fm], bf[fn], acc1[fm][fn], 0, 0, 0);
    }
    __syncthreads();

#pragma unroll
    for (int fn = 0; fn < 4; ++fn) {
        const int col = wv * 64 + fn * 16 + lrow;
        const float bv = b1[col];
#pragma unroll
        for (int fm = 0; fm < 4; ++fm) {
            const int rbase = fm * 16 + (lane >> 4) * 4;
#pragma unroll
            for (int r = 0; r < 4; ++r) {
                const int row = rbase + r;
                const float v = fmaxf(acc1[fm][fn][r] + bv, 0.f);
                unsigned byte = (unsigned)((row * 256 + col) * 2) ^ (unsigned)((row & 7) << 4);
                *(unsigned short*)((char*)lds + byte) = f2bf(v);
            }
        }
    }
    __syncthreads();

    f32x4 acc2[4][4];
#pragma unroll
    for (int fm = 0; fm < 4; ++fm)
#pragma unroll
        for (int fn = 0; fn < 4; ++fn) acc2[fm][fn] = (f32x4)(0.f);

    const unsigned short* W2Base = W2p + ((size_t)(wv * 4) * 8 * 64 + lane) * 8;
    for (int kt = 0; kt < 8; ++kt) {
        short8 a[4], bf[4];
#pragma unroll
        for (int fm = 0; fm < 4; ++fm) {
            const int r = fm * 16 + lrow;
            unsigned byte = (unsigned)((r * 256 + kt * 32 + lk2) * 2) ^ (unsigned)((r & 7) << 4);
            a[fm] = *(const short8*)((const char*)lds + byte);
        }
#pragma unroll
        for (int fn = 0; fn < 4; ++fn)
            bf[fn] = *(const short8*)(W2Base + ((size_t)fn * 8 + kt) * 64 * 8);
#pragma unroll
        for (int fm = 0; fm < 4; ++fm)
#pragma unroll
            for (int fn = 0; fn < 4; ++fn)
                acc2[fm][fn] = __builtin_amdgcn_mfma_f32_16x16x32_bf16(
                    a[fm], bf[fn], acc2[fm][fn], 0, 0, 0);
    }

#pragma unroll
    for (int fn = 0; fn < 4; ++fn) {
        const int col = wv * 64 + fn * 16 + lrow;
        const float bv = b2[col];
#pragma unroll
        for (int fm = 0; fm < 4; ++fm) {
            const int rbase = row0 + fm * 16 + (lane >> 4) * 4;
#pragma unroll
            for (int r = 0; r < 4; ++r) {
                const int row = rbase + r;
                if (row < N) {
                    float v = fmaxf(acc2[fm][fn][r] + bv, 0.f);  // conv1 output ReLU
                    unsigned p = (unsigned)__builtin_amdgcn_cvt_pk_fp8_f32(v, v, 0, false);
                    C8[(size_t)row * 256 + col] = (unsigned char)(p & 0xff);
                }
            }
        }
    }
}

// ---------------- conv2: T1 = relu(A@W3+b3), colsum only (no pass2) ----------------
// pool = Sum_rows T1 ; final W4 matvec happens in head. No LDS, no barriers.

__global__ __launch_bounds__(256) void t1pool_dual(
    const unsigned short* __restrict__ Ad,
    const unsigned short* __restrict__ W1pd, const float* __restrict__ b1d,
    float* __restrict__ poold, int ndb,
    const unsigned short* __restrict__ Aq,
    const unsigned short* __restrict__ W1pq, const float* __restrict__ b1q,
    float* __restrict__ poolq) {
    const unsigned short* A; const unsigned short* W1p; const float* b1;
    float* pool; int row0, N;
    if ((int)blockIdx.x < ndb) {
        A = Ad; W1p = W1pd; b1 = b1d; pool = poold; row0 = blockIdx.x * 64; N = ND;
    } else {
        A = Aq; W1p = W1pq; b1 = b1q; pool = poolq; row0 = 0; N = NQ;
    }

    const int tid = threadIdx.x;
    const int lane = tid & 63;
    const int wv = tid >> 6;
    const int lrow = lane & 15;
    const int lk2 = (lane >> 4) * 8;

    f32x4 acc[4][4];
#pragma unroll
    for (int fm = 0; fm < 4; ++fm)
#pragma unroll
        for (int fn = 0; fn < 4; ++fn) acc[fm][fn] = (f32x4)(0.f);

    const unsigned short* W1Base = W1p + ((size_t)(wv * 4) * 8 * 64 + lane) * 8;
    const unsigned short* Alane = A + (size_t)(row0 + lrow) * 256 + lk2;

#pragma unroll
    for (int kt = 0; kt < 8; ++kt) {
        short8 a[4], bf[4];
#pragma unroll
        for (int fm = 0; fm < 4; ++fm)
            a[fm] = *(const short8*)(Alane + (size_t)(fm * 16) * 256 + kt * 32);
#pragma unroll
        for (int fn = 0; fn < 4; ++fn)
            bf[fn] = *(const short8*)(W1Base + ((size_t)fn * 8 + kt) * 64 * 8);
#pragma unroll
        for (int fm = 0; fm < 4; ++fm)
#pragma unroll
            for (int fn = 0; fn < 4; ++fn)
                acc[fm][fn] = __builtin_amdgcn_mfma_f32_16x16x32_bf16(
                    a[fm], bf[fn], acc[fm][fn], 0, 0, 0);
    }

#pragma unroll
    for (int fn = 0; fn < 4; ++fn) {
        const int col = wv * 64 + fn * 16 + lrow;
        const float bv = b1[col];
        float ps = 0.f;
#pragma unroll
        for (int fm = 0; fm < 4; ++fm) {
            const int rbase = row0 + fm * 16 + (lane >> 4) * 4;
#pragma unroll
            for (int r = 0; r < 4; ++r) {
                const int row = rbase + r;
                if (row < N) ps += fmaxf(acc[fm][fn][r] + bv, 0.f);
            }
        }
        ps += __shfl_xor(ps, 16);
        ps += __shfl_xor(ps, 32);
        if ((lane >> 4) == 0) atomicAdd(&pool[col], ps);
    }
}

// ---------------- head: W4 matvec (exact fp32) + 3-layer MLP ----------------
// poolT1: [0..255] = query T1-pool, [256..511] = data T1-pool

__global__ void mlp_head(const float* __restrict__ poolT1,
                         const float* __restrict__ qW4, const float* __restrict__ qb4,
                         const float* __restrict__ dW4, const float* __restrict__ db4,
                         const float* __restrict__ lW1, const float* __restrict__ lb1,
                         const float* __restrict__ lW2, const float* __restrict__ lb2,
                         const float* __restrict__ lW3, const float* __restrict__ lb3,
                         float* __restrict__ out) {
    __shared__ float h0[512];
    __shared__ float h1[256];
    __shared__ float h2[128];
    const int t = threadIdx.x;  // 256 threads

    // pooled = [qp, dp]; qp = qT1p @ qW4 + NQ*qb4 ; dp = dT1p @ dW4 + ND*db4
    float accq = (float)NQ * qb4[t];
    float accd = (float)ND * db4[t];
    for (int k = 0; k < 256; ++k) {
        accq += poolT1[k] * qW4[(size_t)k * 256 + t];
        accd += poolT1[256 + k] * dW4[(size_t)k * 256 + t];
    }
    h0[t] = accq;
    h0[t + 256] = accd;
    __syncthreads();

    float acc = lb1[t];
    for (int k = 0; k < 512; ++k) acc += h0[k] * lW1[k * 256 + t];
    h1[t] = fmaxf(acc, 0.f);
    __syncthreads();

    if (t < 128) {
        float a = lb2[t];
        for (int k = 0; k < 256; ++k) a += h1[k] * lW2[k * 128 + t];
        h2[t] = fmaxf(a, 0.f);
    }
    __syncthreads();

    if (t < 8) {
        float a = lb3[t];
        for (int k = 0; k < 128; ++k) a += h2[k] * lW3[k * 8 + t];
        out[t] = fmaxf(a, 0.f);
    }
}

// ---------------------------------------------------------------------------

extern "C" void kernel_launch(void* const* d_in, const int* in_sizes, int n_in,
                              void* d_out, int out_size, void* d_ws, size_t ws_size,
                              hipStream_t stream) {
    const float* q_x  = (const float*)d_in[0];
    const float* d_x  = (const float*)d_in[1];
    const int*   q_el = (const int*)d_in[2];
    const int*   d_el = (const int*)d_in[3];
    const float* qW1 = (const float*)d_in[4];  const float* qb1 = (const float*)d_in[5];
    const float* qW2 = (const float*)d_in[6];  const float* qb2 = (const float*)d_in[7];
    const float* qW3 = (const float*)d_in[8];  const float* qb3 = (const float*)d_in[9];
    const float* qW4 = (const float*)d_in[10]; const float* qb4 = (const float*)d_in[11];
    const float* dW1 = (const float*)d_in[12]; const float* db1 = (const float*)d_in[13];
    const float* dW2 = (const float*)d_in[14]; const float* db2 = (const float*)d_in[15];
    const float* dW3 = (const float*)d_in[16]; const float* db3 = (const float*)d_in[17];
    const float* dW4 = (const float*)d_in[18]; const float* db4 = (const float*)d_in[19];
    const float* lW1 = (const float*)d_in[20]; const float* lb1 = (const float*)d_in[21];
    const float* lW2 = (const float*)d_in[22]; const float* lb2 = (const float*)d_in[23];
    const float* lW3 = (const float*)d_in[24]; const float* lb3 = (const float*)d_in[25];
    (void)in_sizes; (void)n_in; (void)out_size; (void)ws_size;

    const int* q_src = q_el;  const int* q_dst = q_el + EQ;
    const int* d_src = d_el;  const int* d_dst = d_el + ED;

    // ---- workspace layout ----
    char* wsb = (char*)d_ws;
    size_t off = 0;
    auto alloc = [&](size_t bytes) { void* p = wsb + off; off += (bytes + 255) & ~(size_t)255; return p; };

    unsigned short* bxd = (unsigned short*)alloc((size_t)ND * FDIM * 2);  // bf16 d_x
    unsigned short* bxq = (unsigned short*)alloc((size_t)NQ * FDIM * 2);  // adjacent
    unsigned short* dag = (unsigned short*)alloc((size_t)ND * FDIM * 2);  // agg1 out (data)
    unsigned short* qag = (unsigned short*)alloc((size_t)NQ * FDIM * 2);
    unsigned char*  h8d = (unsigned char*)alloc((size_t)ND * HDIM);       // conv1 out fp8
    unsigned char*  h8q = (unsigned char*)alloc((size_t)NQ * HDIM);
    unsigned short* had = (unsigned short*)alloc((size_t)ND * HDIM * 2);  // agg2 out bf16
    unsigned short* haq = (unsigned short*)alloc((size_t)(NQ + 64) * HDIM * 2);  // +tail pad
    float* poolT1 = (float*)alloc(512 * 4);   // [q(256), d(256)] T1 column sums
    int* d_deg    = (int*)alloc((size_t)ND * 4);
    int* q_deg    = (int*)alloc((size_t)NQ * 4);   // adjacent to d_deg (one memset)
    int* d_rowptr = (int*)alloc((size_t)(ND + 1) * 4);
    int* d_cursor = (int*)alloc((size_t)ND * 4);
    int* d_csrsrc = (int*)alloc((size_t)ED * 4);
    int* d_bsum   = (int*)alloc(256 * 4);
    int* d_boff   = (int*)alloc(256 * 4);
    int* q_rowptr = (int*)alloc((size_t)(NQ + 1) * 4);
    int* q_cursor = (int*)alloc((size_t)NQ * 4);
    int* q_csrsrc = (int*)alloc((size_t)EQ * 4);
    int* q_bsum   = (int*)alloc(256 * 4);
    int* q_boff   = (int*)alloc(256 * 4);
    unsigned short* pdW1 = (unsigned short*)alloc((size_t)FDIM * 256 * 2);
    unsigned short* pdW2 = (unsigned short*)alloc((size_t)HDIM * 256 * 2);
    unsigned short* pdW3 = (unsigned short*)alloc((size_t)HDIM * 256 * 2);
    unsigned short* pqW1 = (unsigned short*)alloc((size_t)FDIM * 256 * 2);
    unsigned short* pqW2 = (unsigned short*)alloc((size_t)HDIM * 256 * 2);
    unsigned short* pqW3 = (unsigned short*)alloc((size_t)HDIM * 256 * 2);

    hipMemsetAsync(poolT1, 0, 512 * 4, stream);
    hipMemsetAsync(d_deg, 0, (char*)(q_deg + NQ) - (char*)d_deg, stream);

    // ---- prepass: cvt + pack (6 matrices) + count ----
    const int d_eb = (ED + 255) / 256;
    const int q_eb = (EQ + 255) / 256;
    const int d_nb = (ND + 255) / 256;
    const int q_nb = (NQ + 255) / 256;
    {
        PackDesc pd;
        const float* Ws[6] = {dW1, dW2, dW3, qW1, qW2, qW3};
        unsigned short* Wps[6] = {pdW1, pdW2, pdW3, pqW1, pqW2, pqW3};
        int kts[6] = {4, 8, 8, 4, 8, 8};
        int s = 0;
        for (int i = 0; i < 6; ++i) {
            pd.W[i] = Ws[i]; pd.Wp[i] = Wps[i]; pd.KT[i] = kts[i];
            pd.start[i] = s; s += 16 * kts[i];
        }
        for (int i = 6; i < 8; ++i) { pd.W[i] = dW1; pd.Wp[i] = pdW1; pd.KT[i] = 4; pd.start[i] = s; }
        pd.start[8] = s;                       // 640 units
        const int pack_units = s;
        const int pack_b = (s + 3) / 4;        // 160 blocks
        long long nd4 = (long long)ND * FDIM / 4;
        long long n4 = nd4 + (long long)NQ * FDIM / 4;
        const int cvt_b = (int)((n4 + 255) / 256);
        prepass<<<cvt_b + pack_b + d_eb + q_eb, 256, 0, stream>>>(
            d_x, q_x, bxd, nd4, n4, cvt_b, pd, pack_units, pack_b,
            d_dst, d_deg, q_dst, q_deg, d_eb);
    }

    // ---- CSR scan + fill ----
    scan_phase1_both<<<d_nb + q_nb, 256, 0, stream>>>(d_deg, d_rowptr, d_bsum,
                                                      q_deg, q_rowptr, q_bsum, d_nb);
    scan_phase2_both<<<2, 256, 0, stream>>>(d_bsum, d_boff, d_rowptr + ND, d_nb,
                                            q_bsum, q_boff, q_rowptr + NQ, q_nb);
    scan_phase3_both<<<d_nb + q_nb, 256, 0, stream>>>(d_rowptr, d_boff, d_cursor,
                                                      q_rowptr, q_boff, q_cursor, d_nb);
    fill_csr_both<<<d_eb + q_eb, 256, 0, stream>>>(d_src, d_dst, d_cursor, d_csrsrc,
                                                   q_src, q_dst, q_cursor, q_csrsrc, d_eb);

    // ---- GIN conv 1: bf16 agg, staged MLP -> h fp8 ----
    const int ndb = (ND + 63) / 64;  // 782

    gin_agg_dual<FDIM><<<ND + NQ, 64, 0, stream>>>(bxd, d_rowptr, d_csrsrc, dag,
                                                   bxq, q_rowptr, q_csrsrc, qag);
    mlp_dual<FDIM><<<ndb + 1, 256, 0, stream>>>(
        dag, pdW1, db1, pdW2, db2, h8d, ndb,
        qag, pqW1, qb1, pqW2, qb2, h8q);

    // ---- GIN conv 2: fp8 gather agg -> bf16, then T1-pool (pass1 only) ----
    gin_agg_f8_256_dual<<<ND + NQ, 64, 0, stream>>>(
        h8d, d_rowptr, d_csrsrc, had, h8q, q_rowptr, q_csrsrc, haq);
    t1pool_dual<<<ndb + 1, 256, 0, stream>>>(
        had, pdW3, db3, poolT1 + 256, ndb,
        haq, pqW3, qb3, poolT1);

    // ---- head: W4 matvec + 3-layer MLP ----
    mlp_head<<<1, 256, 0, stream>>>(poolT1, qW4, qb4, dW4, db4,
                                    lW1, lb1, lW2, lb2, lW3, lb3, (float*)d_out);
}

// Round 14
// 227.504 us; speedup vs baseline: 1.7071x; 1.0771x over previous
//
#include <hip/hip_runtime.h>
#include <hip/hip_bf16.h>

// ---------------------------------------------------------------------------
// BasicCountNet round 14:
//   - head parallelized: 4 k-split matvec kernels (head_w4/l1/l2/l3) with
//     fp32 atomic accumulation replace the 48us single-block mlp_head.
//   - fp8-x conv1 gather restored (R9, absmax-neutral).
//   - single memset (poolT1/s0/s1/s2/deg contiguous).
//   - rest = R13 (t1pool algebraic W4 elimination, fp8 h, bf16 MFMA MLPs).
// ---------------------------------------------------------------------------

#define NQ 64
#define EQ 512
#define ND 50000
#define ED 600000
#define FDIM 128
#define HDIM 256

typedef __attribute__((ext_vector_type(8))) short short8;
typedef __attribute__((ext_vector_type(4))) float f32x4;
typedef __attribute__((ext_vector_type(2))) float floatx2;
typedef __attribute__((ext_vector_type(4))) unsigned short us4;
typedef __attribute__((ext_vector_type(2))) unsigned short us2;

__device__ __forceinline__ unsigned short f2bf(float f) {
    union { float f; unsigned u; } v; v.f = f;
    unsigned r = v.u + 0x7FFF + ((v.u >> 16) & 1);   // RNE
    return (unsigned short)(r >> 16);
}
__device__ __forceinline__ float bf2f(unsigned short u) {
    union { unsigned u; float f; } v; v.u = ((unsigned)u) << 16;
    return v.f;
}

// ---------------- weight pack descriptor (6 matrices: W1..W3 per graph) ----------------
// Wp layout: [ct(16)][kt(KT)][lane(64)][j(8)]; elem = W[kt*32+(l>>4)*8+j][ct*16+(l&15)]

struct PackDesc {
    const float* W[8];
    unsigned short* Wp[8];
    int KT[8];
    int start[9];
};

__device__ __forceinline__ void pack_unit(const PackDesc& pd, int unit, int l) {
    int m = 0;
    while (m < 7 && unit >= pd.start[m + 1]) ++m;
    const int local = unit - pd.start[m];
    const int KT = pd.KT[m];
    const int kt = local % KT;
    const int ct = local / KT;
    const float* W = pd.W[m];
    unsigned short* Wp = pd.Wp[m];
    const int row = kt * 32 + (l >> 4) * 8;
    const int col = ct * 16 + (l & 15);
    short8 v;
#pragma unroll
    for (int j = 0; j < 8; ++j) v[j] = (short)f2bf(W[(size_t)(row + j) * 256 + col]);
    *(short8*)(Wp + (((size_t)(ct * KT + kt)) * 64 + l) * 8) = v;
}

// ---------------- prepass: cvt(x->fp8) + pack weights + count degrees ----------------

__global__ void prepass(const float* __restrict__ xd, const float* __restrict__ xq,
                        unsigned char* __restrict__ x8, long long nd4, long long n4,
                        int cvt_b, PackDesc pd, int pack_units, int pack_b,
                        const int* __restrict__ d_dst, int* __restrict__ d_deg,
                        const int* __restrict__ q_dst, int* __restrict__ q_deg,
                        int d_eb) {
    const int b = blockIdx.x;
    const int tid = threadIdx.x;
    if (b < cvt_b) {
        long long i = (long long)b * 256 + tid;
        if (i >= n4) return;
        const float* src = (i < nd4) ? (xd + i * 4) : (xq + (i - nd4) * 4);
        float4 v = *(const float4*)src;
        int p = __builtin_amdgcn_cvt_pk_fp8_f32(v.x, v.y, 0, false);
        p = __builtin_amdgcn_cvt_pk_fp8_f32(v.z, v.w, p, true);
        *(unsigned*)(x8 + i * 4) = (unsigned)p;
    } else if (b < cvt_b + pack_b) {
        const int unit = (b - cvt_b) * 4 + (tid >> 6);
        if (unit < pack_units) pack_unit(pd, unit, tid & 63);
    } else {
        const int cb = b - cvt_b - pack_b;
        if (cb < d_eb) {
            int e = cb * 256 + tid;
            if (e < ED) atomicAdd(&d_deg[d_dst[e]], 1);
        } else {
            int e = (cb - d_eb) * 256 + tid;
            if (e < EQ) atomicAdd(&q_deg[q_dst[e]], 1);
        }
    }
}

// ---------------- CSR scan/fill (dual) ----------------

__device__ __forceinline__ void scan1_body(const int* deg, int* rowptr, int* bsum,
                                           int n, int blk) {
    __shared__ int sh[256];
    const int t = threadIdx.x;
    const int i = blk * 256 + t;
    const int v = (i < n) ? deg[i] : 0;
    sh[t] = v;
    __syncthreads();
    for (int off = 1; off < 256; off <<= 1) {
        int x = (t >= off) ? sh[t - off] : 0;
        __syncthreads();
        sh[t] += x;
        __syncthreads();
    }
    if (i < n) rowptr[i] = sh[t] - v;
    if (t == 255) bsum[blk] = sh[255];
}

__global__ void scan_phase1_both(const int* __restrict__ d_deg, int* __restrict__ d_rowptr,
                                 int* __restrict__ d_bsum,
                                 const int* __restrict__ q_deg, int* __restrict__ q_rowptr,
                                 int* __restrict__ q_bsum, int dblocks) {
    int b = blockIdx.x;
    if (b < dblocks) scan1_body(d_deg, d_rowptr, d_bsum, ND, b);
    else             scan1_body(q_deg, q_rowptr, q_bsum, NQ, b - dblocks);
}

__device__ __forceinline__ void scan2_body(const int* bsum, int* boff, int* rowptr_n, int nb) {
    __shared__ int sh[256];
    const int t = threadIdx.x;
    const int v = (t < nb) ? bsum[t] : 0;
    sh[t] = v;
    __syncthreads();
    for (int off = 1; off < 256; off <<= 1) {
        int x = (t >= off) ? sh[t - off] : 0;
        __syncthreads();
        sh[t] += x;
        __syncthreads();
    }
    if (t < nb) boff[t] = sh[t] - v;
    if (t == 255) *rowptr_n = sh[255];
}

__global__ void scan_phase2_both(const int* __restrict__ d_bsum, int* __restrict__ d_boff,
                                 int* __restrict__ d_rowptr_n, int d_nb,
                                 const int* __restrict__ q_bsum, int* __restrict__ q_boff,
                                 int* __restrict__ q_rowptr_n, int q_nb) {
    if (blockIdx.x == 0) scan2_body(d_bsum, d_boff, d_rowptr_n, d_nb);
    else                 scan2_body(q_bsum, q_boff, q_rowptr_n, q_nb);
}

__global__ void scan_phase3_both(int* __restrict__ d_rowptr, const int* __restrict__ d_boff,
                                 int* __restrict__ d_cursor,
                                 int* __restrict__ q_rowptr, const int* __restrict__ q_boff,
                                 int* __restrict__ q_cursor, int dblocks) {
    int b = blockIdx.x;
    if (b < dblocks) {
        int i = b * 256 + threadIdx.x;
        if (i < ND) {
            int r = d_rowptr[i] + d_boff[b];
            d_rowptr[i] = r; d_cursor[i] = r;
        }
    } else {
        int i = (b - dblocks) * 256 + threadIdx.x;
        if (i < NQ) {
            int r = q_rowptr[i] + q_boff[b - dblocks];
            q_rowptr[i] = r; q_cursor[i] = r;
        }
    }
}

__global__ void fill_csr_both(const int* __restrict__ d_src, const int* __restrict__ d_dst,
                              int* __restrict__ d_cursor, int* __restrict__ d_csrsrc,
                              const int* __restrict__ q_src, const int* __restrict__ q_dst,
                              int* __restrict__ q_cursor, int* __restrict__ q_csrsrc,
                              int dblocks) {
    int b = blockIdx.x;
    if (b < dblocks) {
        int e = b * 256 + threadIdx.x;
        if (e < ED) {
            int p = atomicAdd(&d_cursor[d_dst[e]], 1);
            d_csrsrc[p] = d_src[e];
        }
    } else {
        int e = (b - dblocks) * 256 + threadIdx.x;
        if (e < EQ) {
            int p = atomicAdd(&q_cursor[q_dst[e]], 1);
            q_csrsrc[p] = q_src[e];
        }
    }
}

// ---------------- agg conv1: fp8 in (128B rows) / bf16 out, 2 nodes per wave ----------------

__global__ void gin_agg_f8_128_dual(const unsigned char* __restrict__ xd,
                                    const int* __restrict__ rpd, const int* __restrict__ csd,
                                    unsigned short* __restrict__ od,
                                    const unsigned char* __restrict__ xq,
                                    const int* __restrict__ rpq, const int* __restrict__ csq,
                                    unsigned short* __restrict__ oq, int ndpair) {
    const unsigned char* x; const int* rowptr; const int* csr; unsigned short* out; int nb;
    if ((int)blockIdx.x < ndpair) { x = xd; rowptr = rpd; csr = csd; out = od; nb = blockIdx.x; }
    else { x = xq; rowptr = rpq; csr = csq; out = oq; nb = blockIdx.x - ndpair; }

    const int t = threadIdx.x;
    const int node = nb * 2 + (t >> 5);
    const int c = t & 31;

    const int beg = rowptr[node];
    const int end = rowptr[node + 1];

    float a0, a1, a2, a3;
    {
        const unsigned w = *(const unsigned*)(x + (size_t)node * 128 + c * 4);
        floatx2 lo = __builtin_amdgcn_cvt_pk_f32_fp8((int)w, false);
        floatx2 hi = __builtin_amdgcn_cvt_pk_f32_fp8((int)w, true);
        a0 = lo[0]; a1 = lo[1]; a2 = hi[0]; a3 = hi[1];
    }
    for (int j = beg; j < end; ++j) {
        const unsigned w = *(const unsigned*)(x + (size_t)csr[j] * 128 + c * 4);
        floatx2 lo = __builtin_amdgcn_cvt_pk_f32_fp8((int)w, false);
        floatx2 hi = __builtin_amdgcn_cvt_pk_f32_fp8((int)w, true);
        a0 += lo[0]; a1 += lo[1]; a2 += hi[0]; a3 += hi[1];
    }
    us4 r;
    r[0] = f2bf(a0); r[1] = f2bf(a1); r[2] = f2bf(a2); r[3] = f2bf(a3);
    *(us4*)(out + (size_t)node * 128 + c * 4) = r;
}

// ---------------- agg conv2: fp8 in (256B rows) / bf16 out, 1 node per wave ----------------

__global__ void gin_agg_f8_256_dual(const unsigned char* __restrict__ xd,
                                    const int* __restrict__ rpd, const int* __restrict__ csd,
                                    unsigned short* __restrict__ od,
                                    const unsigned char* __restrict__ xq,
                                    const int* __restrict__ rpq, const int* __restrict__ csq,
                                    unsigned short* __restrict__ oq) {
    const unsigned char* x; const int* rowptr; const int* csr; unsigned short* out; int node;
    if ((int)blockIdx.x < ND) { x = xd; rowptr = rpd; csr = csd; out = od; node = blockIdx.x; }
    else { x = xq; rowptr = rpq; csr = csq; out = oq; node = blockIdx.x - ND; }

    const int t = threadIdx.x;
    const int beg = rowptr[node];
    const int end = rowptr[node + 1];

    float a0, a1, a2, a3;
    {
        const unsigned w = *(const unsigned*)(x + (size_t)node * 256 + t * 4);
        floatx2 lo = __builtin_amdgcn_cvt_pk_f32_fp8((int)w, false);
        floatx2 hi = __builtin_amdgcn_cvt_pk_f32_fp8((int)w, true);
        a0 = lo[0]; a1 = lo[1]; a2 = hi[0]; a3 = hi[1];
    }
    int j = beg;
    for (; j + 1 < end; j += 2) {
        const unsigned w0 = *(const unsigned*)(x + (size_t)csr[j] * 256 + t * 4);
        const unsigned w1 = *(const unsigned*)(x + (size_t)csr[j + 1] * 256 + t * 4);
        floatx2 l0 = __builtin_amdgcn_cvt_pk_f32_fp8((int)w0, false);
        floatx2 h0 = __builtin_amdgcn_cvt_pk_f32_fp8((int)w0, true);
        floatx2 l1 = __builtin_amdgcn_cvt_pk_f32_fp8((int)w1, false);
        floatx2 h1 = __builtin_amdgcn_cvt_pk_f32_fp8((int)w1, true);
        a0 += l0[0] + l1[0]; a1 += l0[1] + l1[1];
        a2 += h0[0] + h1[0]; a3 += h0[1] + h1[1];
    }
    if (j < end) {
        const unsigned w0 = *(const unsigned*)(x + (size_t)csr[j] * 256 + t * 4);
        floatx2 l0 = __builtin_amdgcn_cvt_pk_f32_fp8((int)w0, false);
        floatx2 h0 = __builtin_amdgcn_cvt_pk_f32_fp8((int)w0, true);
        a0 += l0[0]; a1 += l0[1]; a2 += h0[0]; a3 += h0[1];
    }
    us4 r;
    r[0] = f2bf(a0); r[1] = f2bf(a1); r[2] = f2bf(a2); r[3] = f2bf(a3);
    *(us4*)(out + (size_t)node * 256 + t * 4) = r;
}

// ---------------- conv1 MLP (R8): staged A, pass1+T1+pass2, fp8 C out ----------------

template <int KIN>
__global__ __launch_bounds__(256) void mlp_dual(
    const unsigned short* __restrict__ Ad,
    const unsigned short* __restrict__ W1pd, const float* __restrict__ b1d,
    const unsigned short* __restrict__ W2pd, const float* __restrict__ b2d,
    unsigned char* __restrict__ C8d, int ndb,
    const unsigned short* __restrict__ Aq,
    const unsigned short* __restrict__ W1pq, const float* __restrict__ b1q,
    const unsigned short* __restrict__ W2pq, const float* __restrict__ b2q,
    unsigned char* __restrict__ C8q) {
    constexpr int KT1 = KIN / 32;
    __shared__ __align__(16) unsigned short lds[64 * 256];

    const unsigned short* A; const unsigned short* W1p; const float* b1;
    const unsigned short* W2p; const float* b2;
    unsigned char* C8; int row0, N;
    if ((int)blockIdx.x < ndb) {
        A = Ad; W1p = W1pd; b1 = b1d; W2p = W2pd; b2 = b2d;
        C8 = C8d; row0 = blockIdx.x * 64; N = ND;
    } else {
        A = Aq; W1p = W1pq; b1 = b1q; W2p = W2pq; b2 = b2q;
        C8 = C8q; row0 = 0; N = NQ;
    }

    const int tid = threadIdx.x;
    const int lane = tid & 63;
    const int wv = tid >> 6;
    const int lrow = lane & 15;
    const int lk2 = (lane >> 4) * 8;
    const int nrows = (N - row0 < 64) ? (N - row0) : 64;

    for (int idx = tid; idx < nrows * (KIN / 8); idx += 256) {
        const int r = idx / (KIN / 8);
        const int k8 = (idx % (KIN / 8)) * 8;
        short8 v = *(const short8*)(A + (size_t)(row0 + r) * KIN + k8);
        unsigned byte = (unsigned)((r * KIN + k8) * 2) ^ (unsigned)((r & 7) << 4);
        *(short8*)((char*)lds + byte) = v;
    }
    __syncthreads();

    f32x4 acc1[4][4];
#pragma unroll
    for (int fm = 0; fm < 4; ++fm)
#pragma unroll
        for (int fn = 0; fn < 4; ++fn) acc1[fm][fn] = (f32x4)(0.f);

    const unsigned short* W1Base = W1p + ((size_t)(wv * 4) * KT1 * 64 + lane) * 8;
    for (int kt = 0; kt < KT1; ++kt) {
        short8 a[4], bf[4];
#pragma unroll
        for (int fm = 0; fm < 4; ++fm) {
            const int r = fm * 16 + lrow;
            unsigned byte = (unsigned)((r * KIN + kt * 32 + lk2) * 2) ^ (unsigned)((r & 7) << 4);
            a[fm] = *(const short8*)((const char*)lds + byte);
        }
#pragma unroll
        for (int fn = 0; fn < 4; ++fn)
            bf[fn] = *(const short8*)(W1Base + ((size_t)fn * KT1 + kt) * 64 * 8);
#pragma unroll
        for (int fm = 0; fm < 4; ++fm)
#pragma unroll
            for (int fn = 0; fn < 4; ++fn)
                acc1[fm][fn] = __builtin_amdgcn_mfma_f32_16x16x32_bf16(
                    a[fm], bf[fn], acc1[fm][fn], 0, 0, 0);
    }
    __syncthreads();

#pragma unroll
    for (int fn = 0; fn < 4; ++fn) {
        const int col = wv * 64 + fn * 16 + lrow;
        const float bv = b1[col];
#pragma unroll
        for (int fm = 0; fm < 4; ++fm) {
            const int rbase = fm * 16 + (lane >> 4) * 4;
#pragma unroll
            for (int r = 0; r < 4; ++r) {
                const int row = rbase + r;
                const float v = fmaxf(acc1[fm][fn][r] + bv, 0.f);
                unsigned byte = (unsigned)((row * 256 + col) * 2) ^ (unsigned)((row & 7) << 4);
                *(unsigned short*)((char*)lds + byte) = f2bf(v);
            }
        }
    }
    __syncthreads();

    f32x4 acc2[4][4];
#pragma unroll
    for (int fm = 0; fm < 4; ++fm)
#pragma unroll
        for (int fn = 0; fn < 4; ++fn) acc2[fm][fn] = (f32x4)(0.f);

    const unsigned short* W2Base = W2p + ((size_t)(wv * 4) * 8 * 64 + lane) * 8;
    for (int kt = 0; kt < 8; ++kt) {
        short8 a[4], bf[4];
#pragma unroll
        for (int fm = 0; fm < 4; ++fm) {
            const int r = fm * 16 + lrow;
            unsigned byte = (unsigned)((r * 256 + kt * 32 + lk2) * 2) ^ (unsigned)((r & 7) << 4);
            a[fm] = *(const short8*)((const char*)lds + byte);
        }
#pragma unroll
        for (int fn = 0; fn < 4; ++fn)
            bf[fn] = *(const short8*)(W2Base + ((size_t)fn * 8 + kt) * 64 * 8);
#pragma unroll
        for (int fm = 0; fm < 4; ++fm)
#pragma unroll
            for (int fn = 0; fn < 4; ++fn)
                acc2[fm][fn] = __builtin_amdgcn_mfma_f32_16x16x32_bf16(
                    a[fm], bf[fn], acc2[fm][fn], 0, 0, 0);
    }

#pragma unroll
    for (int fn = 0; fn < 4; ++fn) {
        const int col = wv * 64 + fn * 16 + lrow;
        const float bv = b2[col];
#pragma unroll
        for (int fm = 0; fm < 4; ++fm) {
            const int rbase = row0 + fm * 16 + (lane >> 4) * 4;
#pragma unroll
            for (int r = 0; r < 4; ++r) {
                const int row = rbase + r;
                if (row < N) {
                    float v = fmaxf(acc2[fm][fn][r] + bv, 0.f);  // conv1 output ReLU
                    unsigned p = (unsigned)__builtin_amdgcn_cvt_pk_fp8_f32(v, v, 0, false);
                    C8[(size_t)row * 256 + col] = (unsigned char)(p & 0xff);
                }
            }
        }
    }
}

// ---------------- conv2: T1 = relu(A@W3+b3), colsum only (no pass2) ----------------

__global__ __launch_bounds__(256) void t1pool_dual(
    const unsigned short* __restrict__ Ad,
    const unsigned short* __restrict__ W1pd, const float* __restrict__ b1d,
    float* __restrict__ poold, int ndb,
    const unsigned short* __restrict__ Aq,
    const unsigned short* __restrict__ W1pq, const float* __restrict__ b1q,
    float* __restrict__ poolq) {
    const unsigned short* A; const unsigned short* W1p; const float* b1;
    float* pool; int row0, N;
    if ((int)blockIdx.x < ndb) {
        A = Ad; W1p = W1pd; b1 = b1d; pool = poold; row0 = blockIdx.x * 64; N = ND;
    } else {
        A = Aq; W1p = W1pq; b1 = b1q; pool = poolq; row0 = 0; N = NQ;
    }

    const int tid = threadIdx.x;
    const int lane = tid & 63;
    const int wv = tid >> 6;
    const int lrow = lane & 15;
    const int lk2 = (lane >> 4) * 8;

    f32x4 acc[4][4];
#pragma unroll
    for (int fm = 0; fm < 4; ++fm)
#pragma unroll
        for (int fn = 0; fn < 4; ++fn) acc[fm][fn] = (f32x4)(0.f);

    const unsigned short* W1Base = W1p + ((size_t)(wv * 4) * 8 * 64 + lane) * 8;
    const unsigned short* Alane = A + (size_t)(row0 + lrow) * 256 + lk2;

#pragma unroll
    for (int kt = 0; kt < 8; ++kt) {
        short8 a[4], bf[4];
#pragma unroll
        for (int fm = 0; fm < 4; ++fm)
            a[fm] = *(const short8*)(Alane + (size_t)(fm * 16) * 256 + kt * 32);
#pragma unroll
        for (int fn = 0; fn < 4; ++fn)
            bf[fn] = *(const short8*)(W1Base + ((size_t)fn * 8 + kt) * 64 * 8);
#pragma unroll
        for (int fm = 0; fm < 4; ++fm)
#pragma unroll
            for (int fn = 0; fn < 4; ++fn)
                acc[fm][fn] = __builtin_amdgcn_mfma_f32_16x16x32_bf16(
                    a[fm], bf[fn], acc[fm][fn], 0, 0, 0);
    }

#pragma unroll
    for (int fn = 0; fn < 4; ++fn) {
        const int col = wv * 64 + fn * 16 + lrow;
        const float bv = b1[col];
        float ps = 0.f;
#pragma unroll
        for (int fm = 0; fm < 4; ++fm) {
            const int rbase = row0 + fm * 16 + (lane >> 4) * 4;
#pragma unroll
            for (int r = 0; r < 4; ++r) {
                const int row = rbase + r;
                if (row < N) ps += fmaxf(acc[fm][fn][r] + bv, 0.f);
            }
        }
        ps += __shfl_xor(ps, 16);
        ps += __shfl_xor(ps, 32);
        if ((lane >> 4) == 0) atomicAdd(&pool[col], ps);
    }
}

// ---------------- parallel head ----------------
// s0[512] = [qT1p@qW4 + NQ*qb4 , dT1p@dW4 + ND*db4]
__global__ void head_w4(const float* __restrict__ poolT1,
                        const float* __restrict__ qW4, const float* __restrict__ qb4,
                        const float* __restrict__ dW4, const float* __restrict__ db4,
                        float* __restrict__ s0) {
    const int b = blockIdx.x;        // 16 blocks: [m(2)][kchunk(8)]
    const int m = b >> 3;
    const int ks = (b & 7) * 32;
    const int t = threadIdx.x;       // 256
    const float* W = m ? dW4 : qW4;
    const float* P = poolT1 + (m ? 256 : 0);
    float acc = 0.f;
    for (int k = ks; k < ks + 32; ++k) acc += P[k] * W[(size_t)k * 256 + t];
    if ((b & 7) == 0) acc += m ? (float)ND * db4[t] : (float)NQ * qb4[t];
    atomicAdd(&s0[m * 256 + t], acc);
}

// s1[256] = s0 @ lW1 + lb1   (relu applied on read downstream)
__global__ void head_l1(const float* __restrict__ s0, const float* __restrict__ lW1,
                        const float* __restrict__ lb1, float* __restrict__ s1) {
    const int ks = blockIdx.x * 32;  // 16 blocks
    const int t = threadIdx.x;       // 256
    float acc = 0.f;
    for (int k = ks; k < ks + 32; ++k) acc += s0[k] * lW1[(size_t)k * 256 + t];
    if (blockIdx.x == 0) acc += lb1[t];
    atomicAdd(&s1[t], acc);
}

// s2[128] = relu(s1) @ lW2 + lb2
__global__ void head_l2(const float* __restrict__ s1, const float* __restrict__ lW2,
                        const float* __restrict__ lb2, float* __restrict__ s2) {
    const int ks = blockIdx.x * 32;  // 8 blocks
    const int t = threadIdx.x;       // 128
    float acc = 0.f;
    for (int k = ks; k < ks + 32; ++k) acc += fmaxf(s1[k], 0.f) * lW2[(size_t)k * 128 + t];
    if (blockIdx.x == 0) acc += lb2[t];
    atomicAdd(&s2[t], acc);
}

// out[8] = relu( relu(s2) @ lW3 + lb3 )
__global__ void head_l3(const float* __restrict__ s2, const float* __restrict__ lW3,
                        const float* __restrict__ lb3, float* __restrict__ out) {
    const int t = threadIdx.x;  // 64
    if (t < 8) {
        float acc = lb3[t];
        for (int k = 0; k < 128; ++k) acc += fmaxf(s2[k], 0.f) * lW3[k * 8 + t];
        out[t] = fmaxf(acc, 0.f);
    }
}

// ---------------------------------------------------------------------------

extern "C" void kernel_launch(void* const* d_in, const int* in_sizes, int n_in,
                              void* d_out, int out_size, void* d_ws, size_t ws_size,
                              hipStream_t stream) {
    const float* q_x  = (const float*)d_in[0];
    const float* d_x  = (const float*)d_in[1];
    const int*   q_el = (const int*)d_in[2];
    const int*   d_el = (const int*)d_in[3];
    const float* qW1 = (const float*)d_in[4];  const float* qb1 = (const float*)d_in[5];
    const float* qW2 = (const float*)d_in[6];  const float* qb2 = (const float*)d_in[7];
    const float* qW3 = (const float*)d_in[8];  const float* qb3 = (const float*)d_in[9];
    const float* qW4 = (const float*)d_in[10]; const float* qb4 = (const float*)d_in[11];
    const float* dW1 = (const float*)d_in[12]; const float* db1 = (const float*)d_in[13];
    const float* dW2 = (const float*)d_in[14]; const float* db2 = (const float*)d_in[15];
    const float* dW3 = (const float*)d_in[16]; const float* db3 = (const float*)d_in[17];
    const float* dW4 = (const float*)d_in[18]; const float* db4 = (const float*)d_in[19];
    const float* lW1 = (const float*)d_in[20]; const float* lb1 = (const float*)d_in[21];
    const float* lW2 = (const float*)d_in[22]; const float* lb2 = (const float*)d_in[23];
    const float* lW3 = (const float*)d_in[24]; const float* lb3 = (const float*)d_in[25];
    (void)in_sizes; (void)n_in; (void)out_size; (void)ws_size;

    const int* q_src = q_el;  const int* q_dst = q_el + EQ;
    const int* d_src = d_el;  const int* d_dst = d_el + ED;

    // ---- workspace layout ----
    char* wsb = (char*)d_ws;
    size_t off = 0;
    auto alloc = [&](size_t bytes) { void* p = wsb + off; off += (bytes + 255) & ~(size_t)255; return p; };

    unsigned char*  x8d = (unsigned char*)alloc((size_t)ND * FDIM);       // fp8 d_x
    unsigned char*  x8q = (unsigned char*)alloc((size_t)NQ * FDIM);       // adjacent
    unsigned short* dag = (unsigned short*)alloc((size_t)ND * FDIM * 2);  // agg1 out bf16
    unsigned short* qag = (unsigned short*)alloc((size_t)NQ * FDIM * 2);
    unsigned char*  h8d = (unsigned char*)alloc((size_t)ND * HDIM);       // conv1 out fp8
    unsigned char*  h8q = (unsigned char*)alloc((size_t)NQ * HDIM);
    unsigned short* had = (unsigned short*)alloc((size_t)ND * HDIM * 2);  // agg2 out bf16
    unsigned short* haq = (unsigned short*)alloc((size_t)(NQ + 64) * HDIM * 2);  // +tail pad
    // ---- contiguous zero region: poolT1, s0, s1, s2, d_deg, q_deg ----
    float* poolT1 = (float*)alloc(512 * 4);
    float* s0     = (float*)alloc(512 * 4);
    float* s1     = (float*)alloc(256 * 4);
    float* s2     = (float*)alloc(128 * 4);
    int* d_deg    = (int*)alloc((size_t)ND * 4);
    int* q_deg    = (int*)alloc((size_t)NQ * 4);
    char* zero_end = wsb + off;
    int* d_rowptr = (int*)alloc((size_t)(ND + 1) * 4);
    int* d_cursor = (int*)alloc((size_t)ND * 4);
    int* d_csrsrc = (int*)alloc((size_t)ED * 4);
    int* d_bsum   = (int*)alloc(256 * 4);
    int* d_boff   = (int*)alloc(256 * 4);
    int* q_rowptr = (int*)alloc((size_t)(NQ + 1) * 4);
    int* q_cursor = (int*)alloc((size_t)NQ * 4);
    int* q_csrsrc = (int*)alloc((size_t)EQ * 4);
    int* q_bsum   = (int*)alloc(256 * 4);
    int* q_boff   = (int*)alloc(256 * 4);
    unsigned short* pdW1 = (unsigned short*)alloc((size_t)FDIM * 256 * 2);
    unsigned short* pdW2 = (unsigned short*)alloc((size_t)HDIM * 256 * 2);
    unsigned short* pdW3 = (unsigned short*)alloc((size_t)HDIM * 256 * 2);
    unsigned short* pqW1 = (unsigned short*)alloc((size_t)FDIM * 256 * 2);
    unsigned short* pqW2 = (unsigned short*)alloc((size_t)HDIM * 256 * 2);
    unsigned short* pqW3 = (unsigned short*)alloc((size_t)HDIM * 256 * 2);

    hipMemsetAsync(poolT1, 0, (size_t)(zero_end - (char*)poolT1), stream);

    // ---- prepass: cvt + pack (6 matrices) + count ----
    const int d_eb = (ED + 255) / 256;
    const int q_eb = (EQ + 255) / 256;
    const int d_nb = (ND + 255) / 256;
    const int q_nb = (NQ + 255) / 256;
    {
        PackDesc pd;
        const float* Ws[6] = {dW1, dW2, dW3, qW1, qW2, qW3};
        unsigned short* Wps[6] = {pdW1, pdW2, pdW3, pqW1, pqW2, pqW3};
        int kts[6] = {4, 8, 8, 4, 8, 8};
        int s = 0;
        for (int i = 0; i < 6; ++i) {
            pd.W[i] = Ws[i]; pd.Wp[i] = Wps[i]; pd.KT[i] = kts[i];
            pd.start[i] = s; s += 16 * kts[i];
        }
        for (int i = 6; i < 8; ++i) { pd.W[i] = dW1; pd.Wp[i] = pdW1; pd.KT[i] = 4; pd.start[i] = s; }
        pd.start[8] = s;                       // 640 units
        const int pack_units = s;
        const int pack_b = (s + 3) / 4;        // 160 blocks
        long long nd4 = (long long)ND * FDIM / 4;
        long long n4 = nd4 + (long long)NQ * FDIM / 4;
        const int cvt_b = (int)((n4 + 255) / 256);
        prepass<<<cvt_b + pack_b + d_eb + q_eb, 256, 0, stream>>>(
            d_x, q_x, x8d, nd4, n4, cvt_b, pd, pack_units, pack_b,
            d_dst, d_deg, q_dst, q_deg, d_eb);
    }

    // ---- CSR scan + fill ----
    scan_phase1_both<<<d_nb + q_nb, 256, 0, stream>>>(d_deg, d_rowptr, d_bsum,
                                                      q_deg, q_rowptr, q_bsum, d_nb);
    scan_phase2_both<<<2, 256, 0, stream>>>(d_bsum, d_boff, d_rowptr + ND, d_nb,
                                            q_bsum, q_boff, q_rowptr + NQ, q_nb);
    scan_phase3_both<<<d_nb + q_nb, 256, 0, stream>>>(d_rowptr, d_boff, d_cursor,
                                                      q_rowptr, q_boff, q_cursor, d_nb);
    fill_csr_both<<<d_eb + q_eb, 256, 0, stream>>>(d_src, d_dst, d_cursor, d_csrsrc,
                                                   q_src, q_dst, q_cursor, q_csrsrc, d_eb);

    // ---- GIN conv 1: fp8 gather agg -> bf16, staged MLP -> h fp8 ----
    const int ndpair = ND / 2;
    const int qpair = NQ / 2;
    const int ndb = (ND + 63) / 64;  // 782

    gin_agg_f8_128_dual<<<ndpair + qpair, 64, 0, stream>>>(
        x8d, d_rowptr, d_csrsrc, dag, x8q, q_rowptr, q_csrsrc, qag, ndpair);
    mlp_dual<FDIM><<<ndb + 1, 256, 0, stream>>>(
        dag, pdW1, db1, pdW2, db2, h8d, ndb,
        qag, pqW1, qb1, pqW2, qb2, h8q);

    // ---- GIN conv 2: fp8 gather agg -> bf16, then T1-pool (pass1 only) ----
    gin_agg_f8_256_dual<<<ND + NQ, 64, 0, stream>>>(
        h8d, d_rowptr, d_csrsrc, had, h8q, q_rowptr, q_csrsrc, haq);
    t1pool_dual<<<ndb + 1, 256, 0, stream>>>(
        had, pdW3, db3, poolT1 + 256, ndb,
        haq, pqW3, qb3, poolT1);

    // ---- parallel head ----
    head_w4<<<16, 256, 0, stream>>>(poolT1, qW4, qb4, dW4, db4, s0);
    head_l1<<<16, 256, 0, stream>>>(s0, lW1, lb1, s1);
    head_l2<<<8, 128, 0, stream>>>(s1, lW2, lb2, s2);
    head_l3<<<1, 64, 0, stream>>>(s2, lW3, lb3, (float*)d_out);
}